// Round 5
// baseline (508.114 us; speedup 1.0000x reference)
//
#include <hip/hip_runtime.h>
#include <cstdint>

// FirstEncoder: B=16 S=512 D=1024 H=16 L=128 V=32000, DH=64.
// Faithful: raw-reshape head split (head (b,h) = contiguous [512,64] block of
// the flat [8192,1024] buffer), score scale 1/32 (DH/2), FFN residual f+f=2f.
// LN-fold: LN(h;g,be)@W = rstd*(h@(g.W)) + (-rstd*mean)*(g^T W) + be^T W,
// applied in GEMM epilogues (W1, Wmu/Wsig) -> removes 2 LN kernels + h3/h5
// round-trips. mu/sig GEMM fused with z = mu + exp(sig)*eps epilogue.

typedef __bf16 bf16;
typedef __bf16 bf16x8 __attribute__((ext_vector_type(8)));
typedef __bf16 bf16x4 __attribute__((ext_vector_type(4)));
typedef float f32x4 __attribute__((ext_vector_type(4)));

#define MFMA16(a, b, c) __builtin_amdgcn_mfma_f32_16x16x32_bf16((a), (b), (c), 0, 0, 0)

#if __has_builtin(__builtin_amdgcn_exp2f)
#define EXP2F(x) __builtin_amdgcn_exp2f(x)
#else
#define EXP2F(x) exp2f(x)
#endif

// async 16B global->LDS (lane i lands at wave-uniform base + i*16)
__device__ __forceinline__ void async16(const bf16* g, bf16* l) {
  __builtin_amdgcn_global_load_lds(
      (const __attribute__((address_space(1))) unsigned int*)g,
      (__attribute__((address_space(3))) unsigned int*)l, 16, 0, 0);
}

// counted waits, pinned against compiler reordering (memory clobber + sched fence)
#define VMWAIT(N)                                        \
  do {                                                   \
    asm volatile("s_waitcnt vmcnt(" #N ")" ::: "memory"); \
    __builtin_amdgcn_sched_barrier(0);                   \
  } while (0)
#define BAR() __builtin_amdgcn_s_barrier()

// ---------------------------------------------------------------------------
// 8x fused weight transpose + f32->bf16, with optional g-scale (LN fold).
// Wt[n*1024 + k] = g[k] * W[k*N + n].
struct TP8 {
  const float* src[8];
  const float* gsrc[8];
  bf16* dst[8];
  int ncol[8];
};
__global__ __launch_bounds__(256) void transpose8_kernel(TP8 p) {
  const int z = blockIdx.z;
  const int N = p.ncol[z];
  const int tk = blockIdx.x * 64, tn = blockIdx.y * 64;
  if (tn >= N) return;
  const float* __restrict__ W = p.src[z];
  bf16* __restrict__ Wt = p.dst[z];
  __shared__ float tile[64][65];
  const int a = threadIdx.x >> 6, b = threadIdx.x & 63;
#pragma unroll
  for (int i = 0; i < 16; ++i) {
    int k = a + i * 4;
    tile[k][b] = W[(size_t)(tk + k) * N + tn + b];
  }
  __syncthreads();
  const float* gsc = p.gsrc[z];
  const float gv = gsc ? gsc[tk + b] : 1.0f;  // k_glob = tk + b in write loop
#pragma unroll
  for (int i = 0; i < 16; ++i) {
    int n = a + i * 4;
    Wt[(size_t)(tn + n) * 1024 + tk + b] = (bf16)(tile[b][n] * gv);
  }
}

// ---------------------------------------------------------------------------
// LN-fold coefficients: c1[n] = sum_k g[k]*W[k][n]; c2[n] = sum_k be[k]*W[k][n].
struct LC3 {
  const float* W[3];
  const float* g[3];
  const float* be[3];
  float* c1[3];
  float* c2[3];
  int N[3];
};
__global__ __launch_bounds__(256) void lncoef_kernel(LC3 p) {
  const int e = blockIdx.y;
  const int N = p.N[e];
  const int n = blockIdx.x * 256 + threadIdx.x;
  if (n >= N) return;
  const float* __restrict__ W = p.W[e];
  const float* __restrict__ g = p.g[e];
  const float* __restrict__ be = p.be[e];
  float a1 = 0.f, a2 = 0.f;
  for (int k = 0; k < 1024; k += 4) {
#pragma unroll
    for (int u = 0; u < 4; ++u) {
      const float v = W[(size_t)(k + u) * N + n];
      a1 += g[k + u] * v;
      a2 += be[k + u] * v;
    }
  }
  p.c1[e][n] = a1;
  p.c2[e][n] = a2;
}

// ---------------------------------------------------------------------------
// Fused embed (*32 + posenc) + LayerNorm1 -> bf16 h1.
__global__ __launch_bounds__(256) void embed_ln_kernel(const int* __restrict__ x,
                                                       const float* __restrict__ emb,
                                                       const float* __restrict__ g,
                                                       const float* __restrict__ be,
                                                       bf16* __restrict__ obf) {
  const int w = threadIdx.x >> 6, lane = threadIdx.x & 63;
  const int row = blockIdx.x * 4 + w;
  const int s = row & 511;
  const int t = x[row];
  const int c0 = lane * 16;
  const float* er = emb + (size_t)t * 1024 + c0;
  float o[16];
#pragma unroll
  for (int i = 0; i < 4; ++i) {
    const float4 e = *(const float4*)(er + i * 4);
    o[i * 4 + 0] = e.x; o[i * 4 + 1] = e.y; o[i * 4 + 2] = e.z; o[i * 4 + 3] = e.w;
  }
#pragma unroll
  for (int p = 0; p < 8; ++p) {
    const int cc = c0 + 2 * p;
    const float freq = __expf((float)cc * (-9.210340371976184f / 1024.0f));
    const float ang = (float)s * freq;
    o[2 * p] = o[2 * p] * 32.0f + __sinf(ang);
    o[2 * p + 1] = o[2 * p + 1] * 32.0f + __cosf(ang);
  }
  float sm = 0.f, q = 0.f;
#pragma unroll
  for (int j = 0; j < 16; ++j) { sm += o[j]; q += o[j] * o[j]; }
#pragma unroll
  for (int off = 1; off < 64; off <<= 1) {
    sm += __shfl_xor(sm, off);
    q += __shfl_xor(q, off);
  }
  const float mean = sm * (1.0f / 1024.0f);
  const float var = q * (1.0f / 1024.0f) - mean * mean;
  const float rstd = rsqrtf(var + 1e-5f);
  bf16 ob[16];
#pragma unroll
  for (int i = 0; i < 4; ++i) {
    const float4 gv = *(const float4*)(g + c0 + i * 4);
    const float4 bv = *(const float4*)(be + c0 + i * 4);
    const float gvv[4] = {gv.x, gv.y, gv.z, gv.w};
    const float bvv[4] = {bv.x, bv.y, bv.z, bv.w};
#pragma unroll
    for (int j = 0; j < 4; ++j)
      ob[i * 4 + j] = (bf16)((o[i * 4 + j] - mean) * rstd * gvv[j] + bvv[j]);
  }
  bf16* dst = obf + (size_t)row * 1024 + c0;
  *(uint4*)dst = *(const uint4*)&ob[0];
  *(uint4*)(dst + 8) = *(const uint4*)&ob[8];
}

// ---------------------------------------------------------------------------
// Row stats for LN-fold: rs[row] = rstd, rm[row] = -rstd*mean (bf16 in).
__global__ __launch_bounds__(256) void rowstats_kernel(const bf16* __restrict__ in,
                                                       float* __restrict__ rs,
                                                       float* __restrict__ rm) {
  const int w = threadIdx.x >> 6, lane = threadIdx.x & 63;
  const int row = blockIdx.x * 4 + w;
  const int c0 = lane * 16;
  const bf16* src = in + (size_t)row * 1024 + c0;
  const bf16x8 v0 = *(const bf16x8*)src;
  const bf16x8 v1 = *(const bf16x8*)(src + 8);
  float s = 0.f, q = 0.f;
#pragma unroll
  for (int j = 0; j < 8; ++j) {
    const float a = (float)v0[j], b = (float)v1[j];
    s += a + b;
    q += a * a + b * b;
  }
#pragma unroll
  for (int off = 1; off < 64; off <<= 1) {
    s += __shfl_xor(s, off);
    q += __shfl_xor(q, off);
  }
  const float mean = s * (1.0f / 1024.0f);
  const float var = q * (1.0f / 1024.0f) - mean * mean;
  const float rstd = rsqrtf(var + 1e-5f);
  if (lane == 0) {
    rs[row] = rstd;
    rm[row] = -rstd * mean;
  }
}

// ---------------------------------------------------------------------------
// 8-phase counted-vmcnt GEMM. BM=128, BN=256, BK=64, 512 thr (8 waves 2Mx4N),
// wave tile 64x64, LDS 96KB (1 block/CU).
// MODE 1: bf16 out = acc + b0 + resid(bf16)                    (Wo)
// MODE 3: bf16 out = 2*(acc + b0)                              (W2, f+f)
// MODE 4: bf16 out = leaky(rs*acc + rm*c1 + c2 + b0)           (W1, LN-fold)
// MODE 6: bf16 out routed to o0/o1/o2 by n-part                (fused QKV)
__device__ __forceinline__ void ld_frags2(const bf16* sm, int rbase, int l15,
                                          int quad, bf16x8 out[2][2]) {
#pragma unroll
  for (int f = 0; f < 2; ++f) {
    const int row = rbase + f * 16 + l15;
    const int rx = row & 7;
#pragma unroll
    for (int h = 0; h < 2; ++h) {
      const int c = (h * 4 + quad) ^ rx;
      out[f][h] = *(const bf16x8*)(sm + (row * 8 + c) * 8);
    }
  }
}

template <int MQ, int NQ>
__device__ __forceinline__ void mma8(const bf16x8 aF[2][2], const bf16x8 bF[2][2],
                                     f32x4 acc[4][4]) {
  __builtin_amdgcn_s_setprio(1);
#pragma unroll
  for (int h = 0; h < 2; ++h)
#pragma unroll
    for (int m2 = 0; m2 < 2; ++m2)
#pragma unroll
      for (int n2 = 0; n2 < 2; ++n2)
        acc[MQ * 2 + m2][NQ * 2 + n2] =
            MFMA16(aF[m2][h], bF[n2][h], acc[MQ * 2 + m2][NQ * 2 + n2]);
  __builtin_amdgcn_s_setprio(0);
}

template <int MODE>
__global__ __launch_bounds__(512, 2) void gemm8_kernel(
    const bf16* __restrict__ A, const bf16* __restrict__ Bt,
    const float* __restrict__ b0f, const float* __restrict__ b1f,
    const float* __restrict__ b2f,
    bf16* __restrict__ o0, bf16* __restrict__ o1, bf16* __restrict__ o2,
    const bf16* __restrict__ residb,
    const float* __restrict__ rsP, const float* __restrict__ rmP,
    int M, int N, int K) {
  (void)M;
  __shared__ __attribute__((aligned(16))) bf16 Asm[2][128 * 64];
  __shared__ __attribute__((aligned(16))) bf16 Bsm[2][256 * 64];
  const int tid = threadIdx.x;
  const int wv = tid >> 6, lane = tid & 63;
  const int quad = lane >> 4, l15 = lane & 15;
  const int wm = wv & 1, wn = wv >> 1;
  const int m0 = blockIdx.x * 128, n0 = blockIdx.y * 256;

  f32x4 acc[4][4];
#pragma unroll
  for (int i = 0; i < 4; ++i)
#pragma unroll
    for (int j = 0; j < 4; ++j) acc[i][j] = {0.f, 0.f, 0.f, 0.f};

  size_t aoff[2], boff[2];
  int slds[2];
#pragma unroll
  for (int i = 0; i < 2; ++i) {
    const int s = tid + i * 512;
    const int r = s >> 3, c = (s & 7) ^ (r & 7);
    aoff[i] = (size_t)(m0 + r) * K + c * 8;
    boff[i] = (size_t)(n0 + r) * K + c * 8;
    slds[i] = s * 8;
  }
  auto stageA = [&](int buf, int t) {
#pragma unroll
    for (int i = 0; i < 2; ++i) async16(A + aoff[i] + t * 64, &Asm[buf][slds[i]]);
  };
  auto stageB = [&](int buf, int hh, int t) {
    const size_t ho = (size_t)hh * 128 * K;
    const int hl = hh * 8192;
#pragma unroll
    for (int i = 0; i < 2; ++i)
      async16(Bt + boff[i] + ho + t * 64, &Bsm[buf][hl + slds[i]]);
  };

  stageB(0, 0, 0); stageB(0, 1, 0); stageA(0, 0);
  stageB(1, 0, 1); stageB(1, 1, 1); stageA(1, 1);
  VMWAIT(6);
  BAR();

  bf16x8 aF[2][2], bF0[2][2], bF1[2][2];
  const int am0 = wm * 64, bn0 = wn * 64;

  auto phases = [&](int ne, int no, bool hn) {
    ld_frags2(&Asm[0][0], am0, l15, quad, aF);
    ld_frags2(&Bsm[0][0], bn0, l15, quad, bF0);
    BAR();
    mma8<0, 0>(aF, bF0, acc);
    BAR();
    ld_frags2(&Bsm[0][0], bn0 + 32, l15, quad, bF1);
    BAR();
    mma8<0, 1>(aF, bF1, acc);
    BAR();
    ld_frags2(&Asm[0][0], am0 + 32, l15, quad, aF);
    if (hn) stageB(0, 0, ne);
    BAR();
    mma8<1, 1>(aF, bF1, acc);
    BAR();
    if (hn) stageB(0, 1, ne);
    BAR();
    mma8<1, 0>(aF, bF0, acc);
    if (hn) { VMWAIT(4); } else { VMWAIT(0); }
    BAR();
    ld_frags2(&Asm[1][0], am0, l15, quad, aF);
    ld_frags2(&Bsm[1][0], bn0, l15, quad, bF0);
    if (hn) stageA(0, ne);
    BAR();
    mma8<0, 0>(aF, bF0, acc);
    BAR();
    ld_frags2(&Bsm[1][0], bn0 + 32, l15, quad, bF1);
    BAR();
    mma8<0, 1>(aF, bF1, acc);
    BAR();
    ld_frags2(&Asm[1][0], am0 + 32, l15, quad, aF);
    if (hn) stageB(1, 0, no);
    BAR();
    mma8<1, 1>(aF, bF1, acc);
    BAR();
    if (hn) { stageB(1, 1, no); stageA(1, no); }
    BAR();
    mma8<1, 0>(aF, bF0, acc);
    if (hn) { VMWAIT(6); }
    BAR();
  };

  const int nIter = K >> 7;
  for (int it = 0; it + 1 < nIter; ++it) phases(2 * it + 2, 2 * it + 3, true);
  phases(0, 0, false);

  const int part = (MODE == 6) ? ((int)blockIdx.y >> 2) : 0;
  bf16* ob = o0;
  const float* bp = b0f;
  if constexpr (MODE == 6) {
    ob = (part == 0) ? o0 : (part == 1 ? o1 : o2);
    bp = (part == 0) ? b0f : (part == 1 ? b1f : b2f);
  }
#pragma unroll
  for (int ni = 0; ni < 4; ++ni) {
    const int col = n0 + wn * 64 + ni * 16 + l15;
    const int cl = (MODE == 6) ? (col - part * 1024) : col;
    const float bv = bp[cl];
    float c1v = 0.f, c2v = 0.f;
    if constexpr (MODE == 4) { c1v = b1f[col]; c2v = b2f[col]; }
#pragma unroll
    for (int mi = 0; mi < 4; ++mi) {
#pragma unroll
      for (int r = 0; r < 4; ++r) {
        const int row = m0 + wm * 64 + mi * 16 + quad * 4 + r;
        const float a = acc[mi][ni][r];
        if constexpr (MODE == 1) {
          const size_t idx = (size_t)row * N + col;
          o0[idx] = (bf16)(a + bv + (float)residb[idx]);
        } else if constexpr (MODE == 4) {
          const float v = rsP[row] * a + rmP[row] * c1v + c2v + bv;
          o0[(size_t)row * N + col] = (bf16)(v > 0.f ? v : 0.01f * v);
        } else if constexpr (MODE == 3) {
          o0[(size_t)row * N + col] = (bf16)(2.0f * (a + bv));
        } else {  // MODE 6
          ob[(size_t)row * 1024 + cl] = (bf16)(a + bv);
        }
      }
    }
  }
}

// ---------------------------------------------------------------------------
// Fused mu|sig GEMM + reparameterization:
//   z[row, c] = mu + exp(sig)*eps, with LN-fold epilogue (rs/rm from h4 stats).
// Tile 32 rows x 256 cols (all of mu|sig), grid (256), 256 thr (4 waves).
// Wave wv owns cols wv*32..+31 of BOTH mu (ni 0,1) and sig (ni 2,3).
// B staging: 256 rows x 8 chunks = 2048 slots = 8 slots/thread (r3 bug was 4).
__global__ __launch_bounds__(256) void gemm_musig_z(
    const bf16* __restrict__ A, const bf16* __restrict__ Bt,
    const float* __restrict__ rsP, const float* __restrict__ rmP,
    const float* __restrict__ c1, const float* __restrict__ c2,
    const float* __restrict__ bmu, const float* __restrict__ bsig,
    const float* __restrict__ eps, float* __restrict__ z) {
  __shared__ __attribute__((aligned(16))) bf16 Asm[2][32 * 64];
  __shared__ __attribute__((aligned(16))) bf16 Bsm[2][256 * 64];
  const int tid = threadIdx.x;
  const int wv = tid >> 6, lane = tid & 63;
  const int quad = lane >> 4, l15 = lane & 15;
  const int m0 = blockIdx.x * 32;

  f32x4 acc[2][4];
#pragma unroll
  for (int i = 0; i < 2; ++i)
#pragma unroll
    for (int j = 0; j < 4; ++j) acc[i][j] = {0.f, 0.f, 0.f, 0.f};

  // A: 256 slots (1/thread); B: 2048 slots (8/thread); XOR chunk swizzle.
  const bf16* Ag;
  int as_;
  {
    const int s = tid;
    const int r = s >> 3, c = (s & 7) ^ (r & 7);
    Ag = A + (size_t)(m0 + r) * 1024 + c * 8;
    as_ = s * 8;
  }
  const bf16* Bg[8];
  int bs_[8];
#pragma unroll
  for (int i = 0; i < 8; ++i) {
    const int s = tid + i * 256;
    const int r = s >> 3, c = (s & 7) ^ (r & 7);
    Bg[i] = Bt + (size_t)r * 1024 + c * 8;
    bs_[i] = s * 8;
  }

  async16(Ag, &Asm[0][as_]);
#pragma unroll
  for (int i = 0; i < 8; ++i) async16(Bg[i], &Bsm[0][bs_[i]]);
  __syncthreads();

  for (int k = 0; k < 16; ++k) {
    const int cur = k & 1, nxt = cur ^ 1;
    bf16x8 af[2][2], bfr[4][2];
#pragma unroll
    for (int mi = 0; mi < 2; ++mi) {
      const int row = mi * 16 + l15;
#pragma unroll
      for (int h = 0; h < 2; ++h) {
        const int pos = (h * 4 + quad) ^ (row & 7);
        af[mi][h] = *(const bf16x8*)(&Asm[cur][(row * 8 + pos) * 8]);
      }
    }
#pragma unroll
    for (int ni = 0; ni < 4; ++ni) {
      const int nr = (ni < 2 ? wv * 32 + ni * 16 : 128 + wv * 32 + (ni - 2) * 16) + l15;
#pragma unroll
      for (int h = 0; h < 2; ++h) {
        const int pos = (h * 4 + quad) ^ (nr & 7);
        bfr[ni][h] = *(const bf16x8*)(&Bsm[cur][(nr * 8 + pos) * 8]);
      }
    }
    if (k + 1 < 16) {
      const int ko = (k + 1) * 64;
      async16(Ag + ko, &Asm[nxt][as_]);
#pragma unroll
      for (int i = 0; i < 8; ++i) async16(Bg[i] + ko, &Bsm[nxt][bs_[i]]);
    }
#pragma unroll
    for (int h = 0; h < 2; ++h)
#pragma unroll
      for (int mi = 0; mi < 2; ++mi)
#pragma unroll
        for (int ni = 0; ni < 4; ++ni)
          acc[mi][ni] = MFMA16(af[mi][h], bfr[ni][h], acc[mi][ni]);
    __syncthreads();
  }

#pragma unroll
  for (int mi = 0; mi < 2; ++mi) {
#pragma unroll
    for (int r = 0; r < 4; ++r) {
      const int row = m0 + mi * 16 + quad * 4 + r;
      const float rs = rsP[row], rm = rmP[row];
#pragma unroll
      for (int cg = 0; cg < 2; ++cg) {
        const int cmu = wv * 32 + cg * 16 + l15;
        const int csg = 128 + cmu;
        const float mu = rs * acc[mi][cg][r] + rm * c1[cmu] + c2[cmu] + bmu[cmu];
        const float sg = rs * acc[mi][2 + cg][r] + rm * c1[csg] + c2[csg] + bsig[cmu];
        z[(size_t)row * 128 + cmu] = mu + __expf(sg) * eps[(size_t)row * 128 + cmu];
      }
    }
  }
}

// ---------------------------------------------------------------------------
// V transpose per head: Vb flat [256 bh][512 kv][64 d] -> VtG [256 bh][64 d][512 kv]
__global__ __launch_bounds__(256) void vtrans_kernel(const bf16* __restrict__ Vb,
                                                     bf16* __restrict__ VtG) {
  __shared__ float t[64][65];
  const int bh = blockIdx.x, kt = blockIdx.y;
  const int tid = threadIdx.x;
  const bf16* src = Vb + (size_t)bh * 32768 + (size_t)kt * 4096;
#pragma unroll
  for (int i = 0; i < 2; ++i) {
    int s = i * 256 + tid;
    int r = s >> 3, c = (s & 7) * 8;
    bf16x8 v = *(const bf16x8*)(src + (size_t)s * 8);
#pragma unroll
    for (int j = 0; j < 8; ++j) t[r][c + j] = (float)v[j];
  }
  __syncthreads();
  bf16* dst = VtG + (size_t)bh * 32768 + kt * 64;
#pragma unroll
  for (int i = 0; i < 2; ++i) {
    int s = i * 256 + tid;
    int d = s >> 3, kc = (s & 7) * 8;
    bf16 tmp[8];
#pragma unroll
    for (int j = 0; j < 8; ++j) tmp[j] = (bf16)t[kc + j][d];
    *(uint4*)(dst + (size_t)d * 512 + kc) = *(const uint4*)tmp;
  }
}

// ---------------------------------------------------------------------------
// Flash-style attention. grid (256 bh, 4 qblk), 256 threads (4 waves).
// No-max softmax (|score/32| small): p = exp2(score * log2e/32) via Q prescale.
__global__ __launch_bounds__(256) void attn_kernel(const bf16* __restrict__ Qg,
                                                   const bf16* __restrict__ Kg,
                                                   const bf16* __restrict__ Vt,
                                                   bf16* __restrict__ ctx) {
  __shared__ __attribute__((aligned(16))) bf16 Ksm[128 * 64];
  __shared__ __attribute__((aligned(16))) bf16 Vsm[64 * 128];
  __shared__ __attribute__((aligned(16))) bf16 Psm[4][16 * 128];
  const int tid = threadIdx.x;
  const int w = tid >> 6, lane = tid & 63;
  const int quad = lane >> 4, l15 = lane & 15;
  const int bh = blockIdx.x;
  const size_t base = (size_t)bh * 32768;
  const bf16* Vth = Vt + base;
  const int qbase = blockIdx.y * 128 + w * 32;
  const f32x4 fz = {0.f, 0.f, 0.f, 0.f};

  bf16x8 a[2][2];
#pragma unroll
  for (int qt = 0; qt < 2; ++qt)
#pragma unroll
    for (int hf = 0; hf < 2; ++hf) {
      bf16x8 tq = *(const bf16x8*)(Qg + base +
                   (size_t)(qbase + qt * 16 + l15) * 64 + hf * 32 + quad * 8);
#pragma unroll
      for (int e = 0; e < 8; ++e) tq[e] = (bf16)((float)tq[e] * 0.045111758f);
      a[qt][hf] = tq;
    }

  f32x4 o[2][4];
  float l_i[2][4];
#pragma unroll
  for (int qt = 0; qt < 2; ++qt)
#pragma unroll
    for (int i = 0; i < 4; ++i) { o[qt][i] = fz; l_i[qt][i] = 0.f; }

  for (int kv0 = 0; kv0 < 512; kv0 += 128) {
#pragma unroll
    for (int i = 0; i < 4; ++i) {
      int s = i * 256 + tid;
      int r = s >> 3, c = (s & 7) ^ (r & 7);
      async16(Kg + base + (size_t)(kv0 + r) * 64 + c * 8, &Ksm[s * 8]);
    }
#pragma unroll
    for (int i = 0; i < 4; ++i) {
      int s = i * 256 + tid;
      int d = s >> 4, cs = s & 15;
      int c = (cs & 8) | ((cs & 7) ^ (d & 7));
      async16(Vth + (size_t)d * 512 + kv0 + c * 8, &Vsm[s * 8]);
    }
    __syncthreads();

    f32x4 sc[2][8];
#pragma unroll
    for (int j = 0; j < 8; ++j) {
      const int n = j * 16 + l15;
      const bf16x8 k0 = *(const bf16x8*)(&Ksm[(n * 8 + (quad ^ (n & 7))) * 8]);
      const bf16x8 k1 = *(const bf16x8*)(&Ksm[(n * 8 + ((4 + quad) ^ (n & 7))) * 8]);
      sc[0][j] = MFMA16(a[0][0], k0, fz);
      sc[0][j] = MFMA16(a[0][1], k1, sc[0][j]);
      sc[1][j] = MFMA16(a[1][0], k0, fz);
      sc[1][j] = MFMA16(a[1][1], k1, sc[1][j]);
    }

    bf16* ps = &Psm[w][0];
#pragma unroll
    for (int qt = 0; qt < 2; ++qt) {
#pragma unroll
      for (int r = 0; r < 4; ++r) {
        const int prow = quad * 4 + r;
        float sum = 0.f;
#pragma unroll
        for (int j = 0; j < 8; ++j) {
          const float p = EXP2F(sc[qt][j][r]);
          sum += p;
          const int col = j * 16 + l15;
          const int cc = col >> 3;
          const int ccs = (cc & 8) | ((cc & 7) ^ (prow & 7));
          ps[prow * 128 + ccs * 8 + (col & 7)] = (bf16)p;
        }
        l_i[qt][r] += sum;
      }
#pragma unroll
      for (int c32 = 0; c32 < 4; ++c32) {
        const int pc = c32 * 4 + quad;
        const int pcs = (pc & 8) | ((pc & 7) ^ (l15 & 7));
        const bf16x8 pf = *(const bf16x8*)(ps + l15 * 128 + pcs * 8);
#pragma unroll
        for (int ni = 0; ni < 4; ++ni) {
          const int d = ni * 16 + l15;
          const int vcs = (pc & 8) | ((pc & 7) ^ (d & 7));
          const bf16x8 vf = *(const bf16x8*)(&Vsm[(d * 16 + vcs) * 8]);
          o[qt][ni] = MFMA16(pf, vf, o[qt][ni]);
        }
      }
    }
    __syncthreads();
  }

#pragma unroll
  for (int qt = 0; qt < 2; ++qt) {
#pragma unroll
    for (int r = 0; r < 4; ++r) {
      float l = l_i[qt][r];
      l += __shfl_xor(l, 1);
      l += __shfl_xor(l, 2);
      l += __shfl_xor(l, 4);
      l += __shfl_xor(l, 8);
      const float inv = 1.0f / l;
#pragma unroll
      for (int ni = 0; ni < 4; ++ni)
        ctx[base + (size_t)(qbase + qt * 16 + quad * 4 + r) * 64 + ni * 16 + l15]
            = (bf16)(o[qt][ni][r] * inv);
    }
  }
}

// ---------------------------------------------------------------------------
extern "C" void kernel_launch(void* const* d_in, const int* in_sizes, int n_in,
                              void* d_out, int out_size, void* d_ws, size_t ws_size,
                              hipStream_t stream) {
  (void)in_sizes; (void)n_in; (void)out_size; (void)ws_size;
  const int* x = (const int*)d_in[0];
  const float* emb = (const float*)d_in[1];
  const float* Wq = (const float*)d_in[2];
  const float* bq = (const float*)d_in[3];
  const float* Wk = (const float*)d_in[4];
  const float* bkb = (const float*)d_in[5];
  const float* Wv = (const float*)d_in[6];
  const float* bv = (const float*)d_in[7];
  const float* Wo = (const float*)d_in[8];
  const float* bo = (const float*)d_in[9];
  const float* g1 = (const float*)d_in[10];
  const float* be1 = (const float*)d_in[11];
  const float* W1 = (const float*)d_in[12];
  const float* bf1 = (const float*)d_in[13];
  const float* W2 = (const float*)d_in[14];
  const float* bf2 = (const float*)d_in[15];
  const float* g2 = (const float*)d_in[16];
  const float* be2 = (const float*)d_in[17];
  const float* g3 = (const float*)d_in[18];
  const float* be3 = (const float*)d_in[19];
  const float* Wmu = (const float*)d_in[20];
  const float* bmu = (const float*)d_in[21];
  const float* Wsig = (const float*)d_in[22];
  const float* bsig = (const float*)d_in[23];
  const float* eps = (const float*)d_in[24];
  float* z = (float*)d_out;

  const int M = 8192, D = 1024;
  char* ws = (char*)d_ws;
  size_t off = 0;
  auto alloc = [&](size_t b) {
    char* p = ws + off;
    off += (b + 255) & ~(size_t)255;
    return p;
  };
  bf16* wqkvT = (bf16*)alloc((size_t)3072 * 1024 * 2);  // [wq^T; wk^T; wv^T]
  bf16* woT = (bf16*)alloc((size_t)1024 * 1024 * 2);
  bf16* w1T = (bf16*)alloc((size_t)1024 * 1024 * 2);    // g2-scaled
  bf16* w2T = (bf16*)alloc((size_t)1024 * 1024 * 2);
  bf16* wmsT = (bf16*)alloc((size_t)256 * 1024 * 2);    // g3-scaled [Wmu^T;Wsig^T]
  bf16* hb = (bf16*)alloc((size_t)M * D * 2);           // h1 (resid for Wo)
  bf16* Qb = (bf16*)alloc((size_t)M * D * 2);
  bf16* Kb = (bf16*)alloc((size_t)M * D * 2);
  bf16* Vb = (bf16*)alloc((size_t)M * D * 2);
  bf16* VtG = (bf16*)alloc((size_t)M * D * 2);
  bf16* Cb = (bf16*)alloc((size_t)M * D * 2);           // ctx
  bf16* h2b = (bf16*)alloc((size_t)M * D * 2);
  bf16* hidb = (bf16*)alloc((size_t)M * D * 2);
  bf16* h4b = (bf16*)alloc((size_t)M * D * 2);
  float* rs2 = (float*)alloc((size_t)M * 4);
  float* rm2 = (float*)alloc((size_t)M * 4);
  float* rs3 = (float*)alloc((size_t)M * 4);
  float* rm3 = (float*)alloc((size_t)M * 4);
  float* c1w1 = (float*)alloc((size_t)1024 * 4);
  float* c2w1 = (float*)alloc((size_t)1024 * 4);
  float* c1ms = (float*)alloc((size_t)256 * 4);
  float* c2ms = (float*)alloc((size_t)256 * 4);

  dim3 b256(256);
  dim3 b512(512);
  TP8 tp;
  for (int i = 0; i < 8; ++i) tp.gsrc[i] = nullptr;
  tp.src[0] = Wq;   tp.dst[0] = wqkvT;                        tp.ncol[0] = 1024;
  tp.src[1] = Wk;   tp.dst[1] = wqkvT + (size_t)1024 * 1024;  tp.ncol[1] = 1024;
  tp.src[2] = Wv;   tp.dst[2] = wqkvT + (size_t)2048 * 1024;  tp.ncol[2] = 1024;
  tp.src[3] = Wo;   tp.dst[3] = woT;                          tp.ncol[3] = 1024;
  tp.src[4] = W1;   tp.dst[4] = w1T;   tp.ncol[4] = 1024;     tp.gsrc[4] = g2;
  tp.src[5] = W2;   tp.dst[5] = w2T;                          tp.ncol[5] = 1024;
  tp.src[6] = Wmu;  tp.dst[6] = wmsT;  tp.ncol[6] = 128;      tp.gsrc[6] = g3;
  tp.src[7] = Wsig; tp.dst[7] = wmsT + (size_t)128 * 1024;    tp.ncol[7] = 128;
  tp.gsrc[7] = g3;
  transpose8_kernel<<<dim3(16, 16, 8), b256, 0, stream>>>(tp);

  LC3 lc;
  lc.W[0] = W1;   lc.g[0] = g2; lc.be[0] = be2; lc.c1[0] = c1w1;       lc.c2[0] = c2w1;       lc.N[0] = 1024;
  lc.W[1] = Wmu;  lc.g[1] = g3; lc.be[1] = be3; lc.c1[1] = c1ms;       lc.c2[1] = c2ms;       lc.N[1] = 128;
  lc.W[2] = Wsig; lc.g[2] = g3; lc.be[2] = be3; lc.c1[2] = c1ms + 128; lc.c2[2] = c2ms + 128; lc.N[2] = 128;
  lncoef_kernel<<<dim3(4, 3), b256, 0, stream>>>(lc);

  embed_ln_kernel<<<2048, b256, 0, stream>>>(x, emb, g1, be1, hb);  // h1

  // fused QKV: N=3072, outputs routed to Qb/Kb/Vb. 768 blocks = 3 full rounds.
  gemm8_kernel<6><<<dim3(64, 12), b512, 0, stream>>>(hb, wqkvT, bq, bkb, bv,
                                                     Qb, Kb, Vb, nullptr,
                                                     nullptr, nullptr, M, 3072, D);
  vtrans_kernel<<<dim3(256, 8), b256, 0, stream>>>(Vb, VtG);
  attn_kernel<<<dim3(256, 4), b256, 0, stream>>>(Qb, Kb, VtG, Cb);

  // Wo + resid -> h2b
  gemm8_kernel<1><<<dim3(64, 4), b512, 0, stream>>>(Cb, woT, bo, nullptr, nullptr,
                                                    h2b, nullptr, nullptr, hb,
                                                    nullptr, nullptr, M, D, D);
  // LN2 stats (fold applied in W1 epilogue)
  rowstats_kernel<<<2048, b256, 0, stream>>>(h2b, rs2, rm2);
  gemm8_kernel<4><<<dim3(64, 4), b512, 0, stream>>>(h2b, w1T, bf1, c1w1, c2w1,
                                                    hidb, nullptr, nullptr, nullptr,
                                                    rs2, rm2, M, D, D);
  gemm8_kernel<3><<<dim3(64, 4), b512, 0, stream>>>(hidb, w2T, bf2, nullptr, nullptr,
                                                    h4b, nullptr, nullptr, nullptr,
                                                    nullptr, nullptr, M, D, D);
  // LN3 stats (fold applied in musig epilogue) + fused mu/sig/z
  rowstats_kernel<<<2048, b256, 0, stream>>>(h4b, rs3, rm3);
  gemm_musig_z<<<dim3(256), b256, 0, stream>>>(h4b, wmsT, rs3, rm3, c1ms, c2ms,
                                               bmu, bsig, eps, z);
}

// Round 7
// 431.563 us; speedup vs baseline: 1.1774x; 1.1774x over previous
//
#include <hip/hip_runtime.h>
#include <cstdint>

// FirstEncoder: B=16 S=512 D=1024 H=16 L=128 V=32000, DH=64.
// Faithful: raw-reshape head split (head (b,h) = contiguous [512,64] block of
// the flat [8192,1024] buffer), score scale 1/32 (DH/2), FFN residual f+f=2f.
// LN-fold: LN(h;g,be)@W = rstd*(h@(g.W)) + (-rstd*mean)*(g^T W) + be^T W,
// applied in GEMM epilogues (W1, Wmu/Wsig) -> removes 2 LN kernels + h3/h5
// round-trips. mu/sig GEMM fused with z = mu + exp(sig)*eps epilogue.
// r6: lncoef re-parallelized (12 blocks/88us -> 768 blocks/atomics, ~4us).
// r7: coefs zeroed by a kernel (no hipMemsetAsync in kernel_launch).

typedef __bf16 bf16;
typedef __bf16 bf16x8 __attribute__((ext_vector_type(8)));
typedef __bf16 bf16x4 __attribute__((ext_vector_type(4)));
typedef float f32x4 __attribute__((ext_vector_type(4)));

#define MFMA16(a, b, c) __builtin_amdgcn_mfma_f32_16x16x32_bf16((a), (b), (c), 0, 0, 0)

#if __has_builtin(__builtin_amdgcn_exp2f)
#define EXP2F(x) __builtin_amdgcn_exp2f(x)
#else
#define EXP2F(x) exp2f(x)
#endif

// async 16B global->LDS (lane i lands at wave-uniform base + i*16)
__device__ __forceinline__ void async16(const bf16* g, bf16* l) {
  __builtin_amdgcn_global_load_lds(
      (const __attribute__((address_space(1))) unsigned int*)g,
      (__attribute__((address_space(3))) unsigned int*)l, 16, 0, 0);
}

// counted waits, pinned against compiler reordering (memory clobber + sched fence)
#define VMWAIT(N)                                        \
  do {                                                   \
    asm volatile("s_waitcnt vmcnt(" #N ")" ::: "memory"); \
    __builtin_amdgcn_sched_barrier(0);                   \
  } while (0)
#define BAR() __builtin_amdgcn_s_barrier()

// ---------------------------------------------------------------------------
// zero 2560 f32 coef slots (capture-safe replacement for hipMemsetAsync)
__global__ __launch_bounds__(256) void zero_coefs_kernel(float* __restrict__ p) {
  p[blockIdx.x * 256 + threadIdx.x] = 0.f;
}

// ---------------------------------------------------------------------------
// 8x fused weight transpose + f32->bf16, with optional g-scale (LN fold).
// Wt[n*1024 + k] = g[k] * W[k*N + n].
struct TP8 {
  const float* src[8];
  const float* gsrc[8];
  bf16* dst[8];
  int ncol[8];
};
__global__ __launch_bounds__(256) void transpose8_kernel(TP8 p) {
  const int z = blockIdx.z;
  const int N = p.ncol[z];
  const int tk = blockIdx.x * 64, tn = blockIdx.y * 64;
  if (tn >= N) return;
  const float* __restrict__ W = p.src[z];
  bf16* __restrict__ Wt = p.dst[z];
  __shared__ float tile[64][65];
  const int a = threadIdx.x >> 6, b = threadIdx.x & 63;
#pragma unroll
  for (int i = 0; i < 16; ++i) {
    int k = a + i * 4;
    tile[k][b] = W[(size_t)(tk + k) * N + tn + b];
  }
  __syncthreads();
  const float* gsc = p.gsrc[z];
  const float gv = gsc ? gsc[tk + b] : 1.0f;  // k_glob = tk + b in write loop
#pragma unroll
  for (int i = 0; i < 16; ++i) {
    int n = a + i * 4;
    Wt[(size_t)(tn + n) * 1024 + tk + b] = (bf16)(tile[b][n] * gv);
  }
}

// ---------------------------------------------------------------------------
// LN-fold coefficients: c1[n] = sum_k g[k]*W[k][n]; c2[n] = sum_k be[k]*W[k][n].
// grid (16 n-tiles, 3 entries, 16 k-splits) = 768 blocks. Block covers
// 64 cols x 64 rows; wave w reads 16 rows x 64 coalesced cols; LDS cross-wave
// reduce; one f32 atomicAdd per column per block (16/column total).
// c1/c2 buffers zeroed by zero_coefs_kernel before launch.
struct LC3 {
  const float* W[3];
  const float* g[3];
  const float* be[3];
  float* c1[3];
  float* c2[3];
  int N[3];
};
__global__ __launch_bounds__(256) void lncoef_kernel(LC3 p) {
  const int e = blockIdx.y;
  const int N = p.N[e];
  const int n0 = blockIdx.x * 64;
  if (n0 >= N) return;
  const int k0 = blockIdx.z * 64;
  const int w = threadIdx.x >> 6, lane = threadIdx.x & 63;
  const int n = n0 + lane;
  const float* __restrict__ W = p.W[e];
  const float* __restrict__ g = p.g[e];
  const float* __restrict__ be = p.be[e];
  float a1 = 0.f, a2 = 0.f;
#pragma unroll
  for (int i = 0; i < 16; ++i) {
    const int k = k0 + w * 16 + i;           // wave-uniform -> scalar g/be loads
    const float v = W[(size_t)k * N + n];    // 64 lanes = 256B coalesced
    a1 += g[k] * v;
    a2 += be[k] * v;
  }
  __shared__ float s1[4][64], s2[4][64];
  s1[w][lane] = a1;
  s2[w][lane] = a2;
  __syncthreads();
  if (w == 0) {
    a1 = s1[0][lane] + s1[1][lane] + s1[2][lane] + s1[3][lane];
    a2 = s2[0][lane] + s2[1][lane] + s2[2][lane] + s2[3][lane];
    atomicAdd(&p.c1[e][n], a1);
    atomicAdd(&p.c2[e][n], a2);
  }
}

// ---------------------------------------------------------------------------
// Fused embed (*32 + posenc) + LayerNorm1 -> bf16 h1.
__global__ __launch_bounds__(256) void embed_ln_kernel(const int* __restrict__ x,
                                                       const float* __restrict__ emb,
                                                       const float* __restrict__ g,
                                                       const float* __restrict__ be,
                                                       bf16* __restrict__ obf) {
  const int w = threadIdx.x >> 6, lane = threadIdx.x & 63;
  const int row = blockIdx.x * 4 + w;
  const int s = row & 511;
  const int t = x[row];
  const int c0 = lane * 16;
  const float* er = emb + (size_t)t * 1024 + c0;
  float o[16];
#pragma unroll
  for (int i = 0; i < 4; ++i) {
    const float4 e = *(const float4*)(er + i * 4);
    o[i * 4 + 0] = e.x; o[i * 4 + 1] = e.y; o[i * 4 + 2] = e.z; o[i * 4 + 3] = e.w;
  }
#pragma unroll
  for (int p = 0; p < 8; ++p) {
    const int cc = c0 + 2 * p;
    const float freq = __expf((float)cc * (-9.210340371976184f / 1024.0f));
    const float ang = (float)s * freq;
    o[2 * p] = o[2 * p] * 32.0f + __sinf(ang);
    o[2 * p + 1] = o[2 * p + 1] * 32.0f + __cosf(ang);
  }
  float sm = 0.f, q = 0.f;
#pragma unroll
  for (int j = 0; j < 16; ++j) { sm += o[j]; q += o[j] * o[j]; }
#pragma unroll
  for (int off = 1; off < 64; off <<= 1) {
    sm += __shfl_xor(sm, off);
    q += __shfl_xor(q, off);
  }
  const float mean = sm * (1.0f / 1024.0f);
  const float var = q * (1.0f / 1024.0f) - mean * mean;
  const float rstd = rsqrtf(var + 1e-5f);
  bf16 ob[16];
#pragma unroll
  for (int i = 0; i < 4; ++i) {
    const float4 gv = *(const float4*)(g + c0 + i * 4);
    const float4 bv = *(const float4*)(be + c0 + i * 4);
    const float gvv[4] = {gv.x, gv.y, gv.z, gv.w};
    const float bvv[4] = {bv.x, bv.y, bv.z, bv.w};
#pragma unroll
    for (int j = 0; j < 4; ++j)
      ob[i * 4 + j] = (bf16)((o[i * 4 + j] - mean) * rstd * gvv[j] + bvv[j]);
  }
  bf16* dst = obf + (size_t)row * 1024 + c0;
  *(uint4*)dst = *(const uint4*)&ob[0];
  *(uint4*)(dst + 8) = *(const uint4*)&ob[8];
}

// ---------------------------------------------------------------------------
// Row stats for LN-fold: rs[row] = rstd, rm[row] = -rstd*mean (bf16 in).
__global__ __launch_bounds__(256) void rowstats_kernel(const bf16* __restrict__ in,
                                                       float* __restrict__ rs,
                                                       float* __restrict__ rm) {
  const int w = threadIdx.x >> 6, lane = threadIdx.x & 63;
  const int row = blockIdx.x * 4 + w;
  const int c0 = lane * 16;
  const bf16* src = in + (size_t)row * 1024 + c0;
  const bf16x8 v0 = *(const bf16x8*)src;
  const bf16x8 v1 = *(const bf16x8*)(src + 8);
  float s = 0.f, q = 0.f;
#pragma unroll
  for (int j = 0; j < 8; ++j) {
    const float a = (float)v0[j], b = (float)v1[j];
    s += a + b;
    q += a * a + b * b;
  }
#pragma unroll
  for (int off = 1; off < 64; off <<= 1) {
    s += __shfl_xor(s, off);
    q += __shfl_xor(q, off);
  }
  const float mean = s * (1.0f / 1024.0f);
  const float var = q * (1.0f / 1024.0f) - mean * mean;
  const float rstd = rsqrtf(var + 1e-5f);
  if (lane == 0) {
    rs[row] = rstd;
    rm[row] = -rstd * mean;
  }
}

// ---------------------------------------------------------------------------
// 8-phase counted-vmcnt GEMM. BM=128, BN=256, BK=64, 512 thr (8 waves 2Mx4N),
// wave tile 64x64, LDS 96KB (1 block/CU).
// MODE 1: bf16 out = acc + b0 + resid(bf16)                    (Wo)
// MODE 3: bf16 out = 2*(acc + b0)                              (W2, f+f)
// MODE 4: bf16 out = leaky(rs*acc + rm*c1 + c2 + b0)           (W1, LN-fold)
// MODE 6: bf16 out routed to o0/o1/o2 by n-part                (fused QKV)
__device__ __forceinline__ void ld_frags2(const bf16* sm, int rbase, int l15,
                                          int quad, bf16x8 out[2][2]) {
#pragma unroll
  for (int f = 0; f < 2; ++f) {
    const int row = rbase + f * 16 + l15;
    const int rx = row & 7;
#pragma unroll
    for (int h = 0; h < 2; ++h) {
      const int c = (h * 4 + quad) ^ rx;
      out[f][h] = *(const bf16x8*)(sm + (row * 8 + c) * 8);
    }
  }
}

template <int MQ, int NQ>
__device__ __forceinline__ void mma8(const bf16x8 aF[2][2], const bf16x8 bF[2][2],
                                     f32x4 acc[4][4]) {
  __builtin_amdgcn_s_setprio(1);
#pragma unroll
  for (int h = 0; h < 2; ++h)
#pragma unroll
    for (int m2 = 0; m2 < 2; ++m2)
#pragma unroll
      for (int n2 = 0; n2 < 2; ++n2)
        acc[MQ * 2 + m2][NQ * 2 + n2] =
            MFMA16(aF[m2][h], bF[n2][h], acc[MQ * 2 + m2][NQ * 2 + n2]);
  __builtin_amdgcn_s_setprio(0);
}

template <int MODE>
__global__ __launch_bounds__(512, 2) void gemm8_kernel(
    const bf16* __restrict__ A, const bf16* __restrict__ Bt,
    const float* __restrict__ b0f, const float* __restrict__ b1f,
    const float* __restrict__ b2f,
    bf16* __restrict__ o0, bf16* __restrict__ o1, bf16* __restrict__ o2,
    const bf16* __restrict__ residb,
    const float* __restrict__ rsP, const float* __restrict__ rmP,
    int M, int N, int K) {
  (void)M;
  __shared__ __attribute__((aligned(16))) bf16 Asm[2][128 * 64];
  __shared__ __attribute__((aligned(16))) bf16 Bsm[2][256 * 64];
  const int tid = threadIdx.x;
  const int wv = tid >> 6, lane = tid & 63;
  const int quad = lane >> 4, l15 = lane & 15;
  const int wm = wv & 1, wn = wv >> 1;
  const int m0 = blockIdx.x * 128, n0 = blockIdx.y * 256;

  f32x4 acc[4][4];
#pragma unroll
  for (int i = 0; i < 4; ++i)
#pragma unroll
    for (int j = 0; j < 4; ++j) acc[i][j] = {0.f, 0.f, 0.f, 0.f};

  size_t aoff[2], boff[2];
  int slds[2];
#pragma unroll
  for (int i = 0; i < 2; ++i) {
    const int s = tid + i * 512;
    const int r = s >> 3, c = (s & 7) ^ (r & 7);
    aoff[i] = (size_t)(m0 + r) * K + c * 8;
    boff[i] = (size_t)(n0 + r) * K + c * 8;
    slds[i] = s * 8;
  }
  auto stageA = [&](int buf, int t) {
#pragma unroll
    for (int i = 0; i < 2; ++i) async16(A + aoff[i] + t * 64, &Asm[buf][slds[i]]);
  };
  auto stageB = [&](int buf, int hh, int t) {
    const size_t ho = (size_t)hh * 128 * K;
    const int hl = hh * 8192;
#pragma unroll
    for (int i = 0; i < 2; ++i)
      async16(Bt + boff[i] + ho + t * 64, &Bsm[buf][hl + slds[i]]);
  };

  stageB(0, 0, 0); stageB(0, 1, 0); stageA(0, 0);
  stageB(1, 0, 1); stageB(1, 1, 1); stageA(1, 1);
  VMWAIT(6);
  BAR();

  bf16x8 aF[2][2], bF0[2][2], bF1[2][2];
  const int am0 = wm * 64, bn0 = wn * 64;

  auto phases = [&](int ne, int no, bool hn) {
    ld_frags2(&Asm[0][0], am0, l15, quad, aF);
    ld_frags2(&Bsm[0][0], bn0, l15, quad, bF0);
    BAR();
    mma8<0, 0>(aF, bF0, acc);
    BAR();
    ld_frags2(&Bsm[0][0], bn0 + 32, l15, quad, bF1);
    BAR();
    mma8<0, 1>(aF, bF1, acc);
    BAR();
    ld_frags2(&Asm[0][0], am0 + 32, l15, quad, aF);
    if (hn) stageB(0, 0, ne);
    BAR();
    mma8<1, 1>(aF, bF1, acc);
    BAR();
    if (hn) stageB(0, 1, ne);
    BAR();
    mma8<1, 0>(aF, bF0, acc);
    if (hn) { VMWAIT(4); } else { VMWAIT(0); }
    BAR();
    ld_frags2(&Asm[1][0], am0, l15, quad, aF);
    ld_frags2(&Bsm[1][0], bn0, l15, quad, bF0);
    if (hn) stageA(0, ne);
    BAR();
    mma8<0, 0>(aF, bF0, acc);
    BAR();
    ld_frags2(&Bsm[1][0], bn0 + 32, l15, quad, bF1);
    BAR();
    mma8<0, 1>(aF, bF1, acc);
    BAR();
    ld_frags2(&Asm[1][0], am0 + 32, l15, quad, aF);
    if (hn) stageB(1, 0, no);
    BAR();
    mma8<1, 1>(aF, bF1, acc);
    BAR();
    if (hn) { stageB(1, 1, no); stageA(1, no); }
    BAR();
    mma8<1, 0>(aF, bF0, acc);
    if (hn) { VMWAIT(6); }
    BAR();
  };

  const int nIter = K >> 7;
  for (int it = 0; it + 1 < nIter; ++it) phases(2 * it + 2, 2 * it + 3, true);
  phases(0, 0, false);

  const int part = (MODE == 6) ? ((int)blockIdx.y >> 2) : 0;
  bf16* ob = o0;
  const float* bp = b0f;
  if constexpr (MODE == 6) {
    ob = (part == 0) ? o0 : (part == 1 ? o1 : o2);
    bp = (part == 0) ? b0f : (part == 1 ? b1f : b2f);
  }
#pragma unroll
  for (int ni = 0; ni < 4; ++ni) {
    const int col = n0 + wn * 64 + ni * 16 + l15;
    const int cl = (MODE == 6) ? (col - part * 1024) : col;
    const float bv = bp[cl];
    float c1v = 0.f, c2v = 0.f;
    if constexpr (MODE == 4) { c1v = b1f[col]; c2v = b2f[col]; }
#pragma unroll
    for (int mi = 0; mi < 4; ++mi) {
#pragma unroll
      for (int r = 0; r < 4; ++r) {
        const int row = m0 + wm * 64 + mi * 16 + quad * 4 + r;
        const float a = acc[mi][ni][r];
        if constexpr (MODE == 1) {
          const size_t idx = (size_t)row * N + col;
          o0[idx] = (bf16)(a + bv + (float)residb[idx]);
        } else if constexpr (MODE == 4) {
          const float v = rsP[row] * a + rmP[row] * c1v + c2v + bv;
          o0[(size_t)row * N + col] = (bf16)(v > 0.f ? v : 0.01f * v);
        } else if constexpr (MODE == 3) {
          o0[(size_t)row * N + col] = (bf16)(2.0f * (a + bv));
        } else {  // MODE 6
          ob[(size_t)row * 1024 + cl] = (bf16)(a + bv);
        }
      }
    }
  }
}

// ---------------------------------------------------------------------------
// Fused mu|sig GEMM + reparameterization:
//   z[row, c] = mu + exp(sig)*eps, with LN-fold epilogue (rs/rm from h4 stats).
// Tile 32 rows x 256 cols (all of mu|sig), grid (256), 256 thr (4 waves).
// Wave wv owns cols wv*32..+31 of BOTH mu (ni 0,1) and sig (ni 2,3).
// B staging: 256 rows x 8 chunks = 2048 slots = 8 slots/thread.
__global__ __launch_bounds__(256) void gemm_musig_z(
    const bf16* __restrict__ A, const bf16* __restrict__ Bt,
    const float* __restrict__ rsP, const float* __restrict__ rmP,
    const float* __restrict__ c1, const float* __restrict__ c2,
    const float* __restrict__ bmu, const float* __restrict__ bsig,
    const float* __restrict__ eps, float* __restrict__ z) {
  __shared__ __attribute__((aligned(16))) bf16 Asm[2][32 * 64];
  __shared__ __attribute__((aligned(16))) bf16 Bsm[2][256 * 64];
  const int tid = threadIdx.x;
  const int wv = tid >> 6, lane = tid & 63;
  const int quad = lane >> 4, l15 = lane & 15;
  const int m0 = blockIdx.x * 32;

  f32x4 acc[2][4];
#pragma unroll
  for (int i = 0; i < 2; ++i)
#pragma unroll
    for (int j = 0; j < 4; ++j) acc[i][j] = {0.f, 0.f, 0.f, 0.f};

  // A: 256 slots (1/thread); B: 2048 slots (8/thread); XOR chunk swizzle.
  const bf16* Ag;
  int as_;
  {
    const int s = tid;
    const int r = s >> 3, c = (s & 7) ^ (r & 7);
    Ag = A + (size_t)(m0 + r) * 1024 + c * 8;
    as_ = s * 8;
  }
  const bf16* Bg[8];
  int bs_[8];
#pragma unroll
  for (int i = 0; i < 8; ++i) {
    const int s = tid + i * 256;
    const int r = s >> 3, c = (s & 7) ^ (r & 7);
    Bg[i] = Bt + (size_t)r * 1024 + c * 8;
    bs_[i] = s * 8;
  }

  async16(Ag, &Asm[0][as_]);
#pragma unroll
  for (int i = 0; i < 8; ++i) async16(Bg[i], &Bsm[0][bs_[i]]);
  __syncthreads();

  for (int k = 0; k < 16; ++k) {
    const int cur = k & 1, nxt = cur ^ 1;
    bf16x8 af[2][2], bfr[4][2];
#pragma unroll
    for (int mi = 0; mi < 2; ++mi) {
      const int row = mi * 16 + l15;
#pragma unroll
      for (int h = 0; h < 2; ++h) {
        const int pos = (h * 4 + quad) ^ (row & 7);
        af[mi][h] = *(const bf16x8*)(&Asm[cur][(row * 8 + pos) * 8]);
      }
    }
#pragma unroll
    for (int ni = 0; ni < 4; ++ni) {
      const int nr = (ni < 2 ? wv * 32 + ni * 16 : 128 + wv * 32 + (ni - 2) * 16) + l15;
#pragma unroll
      for (int h = 0; h < 2; ++h) {
        const int pos = (h * 4 + quad) ^ (nr & 7);
        bfr[ni][h] = *(const bf16x8*)(&Bsm[cur][(nr * 8 + pos) * 8]);
      }
    }
    if (k + 1 < 16) {
      const int ko = (k + 1) * 64;
      async16(Ag + ko, &Asm[nxt][as_]);
#pragma unroll
      for (int i = 0; i < 8; ++i) async16(Bg[i] + ko, &Bsm[nxt][bs_[i]]);
    }
#pragma unroll
    for (int h = 0; h < 2; ++h)
#pragma unroll
      for (int mi = 0; mi < 2; ++mi)
#pragma unroll
        for (int ni = 0; ni < 4; ++ni)
          acc[mi][ni] = MFMA16(af[mi][h], bfr[ni][h], acc[mi][ni]);
    __syncthreads();
  }

#pragma unroll
  for (int mi = 0; mi < 2; ++mi) {
#pragma unroll
    for (int r = 0; r < 4; ++r) {
      const int row = m0 + mi * 16 + quad * 4 + r;
      const float rs = rsP[row], rm = rmP[row];
#pragma unroll
      for (int cg = 0; cg < 2; ++cg) {
        const int cmu = wv * 32 + cg * 16 + l15;
        const int csg = 128 + cmu;
        const float mu = rs * acc[mi][cg][r] + rm * c1[cmu] + c2[cmu] + bmu[cmu];
        const float sg = rs * acc[mi][2 + cg][r] + rm * c1[csg] + c2[csg] + bsig[cmu];
        z[(size_t)row * 128 + cmu] = mu + __expf(sg) * eps[(size_t)row * 128 + cmu];
      }
    }
  }
}

// ---------------------------------------------------------------------------
// V transpose per head: Vb flat [256 bh][512 kv][64 d] -> VtG [256 bh][64 d][512 kv]
__global__ __launch_bounds__(256) void vtrans_kernel(const bf16* __restrict__ Vb,
                                                     bf16* __restrict__ VtG) {
  __shared__ float t[64][65];
  const int bh = blockIdx.x, kt = blockIdx.y;
  const int tid = threadIdx.x;
  const bf16* src = Vb + (size_t)bh * 32768 + (size_t)kt * 4096;
#pragma unroll
  for (int i = 0; i < 2; ++i) {
    int s = i * 256 + tid;
    int r = s >> 3, c = (s & 7) * 8;
    bf16x8 v = *(const bf16x8*)(src + (size_t)s * 8);
#pragma unroll
    for (int j = 0; j < 8; ++j) t[r][c + j] = (float)v[j];
  }
  __syncthreads();
  bf16* dst = VtG + (size_t)bh * 32768 + kt * 64;
#pragma unroll
  for (int i = 0; i < 2; ++i) {
    int s = i * 256 + tid;
    int d = s >> 3, kc = (s & 7) * 8;
    bf16 tmp[8];
#pragma unroll
    for (int j = 0; j < 8; ++j) tmp[j] = (bf16)t[kc + j][d];
    *(uint4*)(dst + (size_t)d * 512 + kc) = *(const uint4*)tmp;
  }
}

// ---------------------------------------------------------------------------
// Flash-style attention. grid (256 bh, 4 qblk), 256 threads (4 waves).
// No-max softmax (|score/32| small): p = exp2(score * log2e/32) via Q prescale.
__global__ __launch_bounds__(256) void attn_kernel(const bf16* __restrict__ Qg,
                                                   const bf16* __restrict__ Kg,
                                                   const bf16* __restrict__ Vt,
                                                   bf16* __restrict__ ctx) {
  __shared__ __attribute__((aligned(16))) bf16 Ksm[128 * 64];
  __shared__ __attribute__((aligned(16))) bf16 Vsm[64 * 128];
  __shared__ __attribute__((aligned(16))) bf16 Psm[4][16 * 128];
  const int tid = threadIdx.x;
  const int w = tid >> 6, lane = tid & 63;
  const int quad = lane >> 4, l15 = lane & 15;
  const int bh = blockIdx.x;
  const size_t base = (size_t)bh * 32768;
  const bf16* Vth = Vt + base;
  const int qbase = blockIdx.y * 128 + w * 32;
  const f32x4 fz = {0.f, 0.f, 0.f, 0.f};

  bf16x8 a[2][2];
#pragma unroll
  for (int qt = 0; qt < 2; ++qt)
#pragma unroll
    for (int hf = 0; hf < 2; ++hf) {
      bf16x8 tq = *(const bf16x8*)(Qg + base +
                   (size_t)(qbase + qt * 16 + l15) * 64 + hf * 32 + quad * 8);
#pragma unroll
      for (int e = 0; e < 8; ++e) tq[e] = (bf16)((float)tq[e] * 0.045111758f);
      a[qt][hf] = tq;
    }

  f32x4 o[2][4];
  float l_i[2][4];
#pragma unroll
  for (int qt = 0; qt < 2; ++qt)
#pragma unroll
    for (int i = 0; i < 4; ++i) { o[qt][i] = fz; l_i[qt][i] = 0.f; }

  for (int kv0 = 0; kv0 < 512; kv0 += 128) {
#pragma unroll
    for (int i = 0; i < 4; ++i) {
      int s = i * 256 + tid;
      int r = s >> 3, c = (s & 7) ^ (r & 7);
      async16(Kg + base + (size_t)(kv0 + r) * 64 + c * 8, &Ksm[s * 8]);
    }
#pragma unroll
    for (int i = 0; i < 4; ++i) {
      int s = i * 256 + tid;
      int d = s >> 4, cs = s & 15;
      int c = (cs & 8) | ((cs & 7) ^ (d & 7));
      async16(Vth + (size_t)d * 512 + kv0 + c * 8, &Vsm[s * 8]);
    }
    __syncthreads();

    f32x4 sc[2][8];
#pragma unroll
    for (int j = 0; j < 8; ++j) {
      const int n = j * 16 + l15;
      const bf16x8 k0 = *(const bf16x8*)(&Ksm[(n * 8 + (quad ^ (n & 7))) * 8]);
      const bf16x8 k1 = *(const bf16x8*)(&Ksm[(n * 8 + ((4 + quad) ^ (n & 7))) * 8]);
      sc[0][j] = MFMA16(a[0][0], k0, fz);
      sc[0][j] = MFMA16(a[0][1], k1, sc[0][j]);
      sc[1][j] = MFMA16(a[1][0], k0, fz);
      sc[1][j] = MFMA16(a[1][1], k1, sc[1][j]);
    }

    bf16* ps = &Psm[w][0];
#pragma unroll
    for (int qt = 0; qt < 2; ++qt) {
#pragma unroll
      for (int r = 0; r < 4; ++r) {
        const int prow = quad * 4 + r;
        float sum = 0.f;
#pragma unroll
        for (int j = 0; j < 8; ++j) {
          const float p = EXP2F(sc[qt][j][r]);
          sum += p;
          const int col = j * 16 + l15;
          const int cc = col >> 3;
          const int ccs = (cc & 8) | ((cc & 7) ^ (prow & 7));
          ps[prow * 128 + ccs * 8 + (col & 7)] = (bf16)p;
        }
        l_i[qt][r] += sum;
      }
#pragma unroll
      for (int c32 = 0; c32 < 4; ++c32) {
        const int pc = c32 * 4 + quad;
        const int pcs = (pc & 8) | ((pc & 7) ^ (l15 & 7));
        const bf16x8 pf = *(const bf16x8*)(ps + l15 * 128 + pcs * 8);
#pragma unroll
        for (int ni = 0; ni < 4; ++ni) {
          const int d = ni * 16 + l15;
          const int vcs = (pc & 8) | ((pc & 7) ^ (d & 7));
          const bf16x8 vf = *(const bf16x8*)(&Vsm[(d * 16 + vcs) * 8]);
          o[qt][ni] = MFMA16(pf, vf, o[qt][ni]);
        }
      }
    }
    __syncthreads();
  }

#pragma unroll
  for (int qt = 0; qt < 2; ++qt) {
#pragma unroll
    for (int r = 0; r < 4; ++r) {
      float l = l_i[qt][r];
      l += __shfl_xor(l, 1);
      l += __shfl_xor(l, 2);
      l += __shfl_xor(l, 4);
      l += __shfl_xor(l, 8);
      const float inv = 1.0f / l;
#pragma unroll
      for (int ni = 0; ni < 4; ++ni)
        ctx[base + (size_t)(qbase + qt * 16 + quad * 4 + r) * 64 + ni * 16 + l15]
            = (bf16)(o[qt][ni][r] * inv);
    }
  }
}

// ---------------------------------------------------------------------------
extern "C" void kernel_launch(void* const* d_in, const int* in_sizes, int n_in,
                              void* d_out, int out_size, void* d_ws, size_t ws_size,
                              hipStream_t stream) {
  (void)in_sizes; (void)n_in; (void)out_size; (void)ws_size;
  const int* x = (const int*)d_in[0];
  const float* emb = (const float*)d_in[1];
  const float* Wq = (const float*)d_in[2];
  const float* bq = (const float*)d_in[3];
  const float* Wk = (const float*)d_in[4];
  const float* bkb = (const float*)d_in[5];
  const float* Wv = (const float*)d_in[6];
  const float* bv = (const float*)d_in[7];
  const float* Wo = (const float*)d_in[8];
  const float* bo = (const float*)d_in[9];
  const float* g1 = (const float*)d_in[10];
  const float* be1 = (const float*)d_in[11];
  const float* W1 = (const float*)d_in[12];
  const float* bf1 = (const float*)d_in[13];
  const float* W2 = (const float*)d_in[14];
  const float* bf2 = (const float*)d_in[15];
  const float* g2 = (const float*)d_in[16];
  const float* be2 = (const float*)d_in[17];
  const float* g3 = (const float*)d_in[18];
  const float* be3 = (const float*)d_in[19];
  const float* Wmu = (const float*)d_in[20];
  const float* bmu = (const float*)d_in[21];
  const float* Wsig = (const float*)d_in[22];
  const float* bsig = (const float*)d_in[23];
  const float* eps = (const float*)d_in[24];
  float* z = (float*)d_out;

  const int M = 8192, D = 1024;
  char* ws = (char*)d_ws;
  size_t off = 0;
  auto alloc = [&](size_t b) {
    char* p = ws + off;
    off += (b + 255) & ~(size_t)255;
    return p;
  };
  bf16* wqkvT = (bf16*)alloc((size_t)3072 * 1024 * 2);  // [wq^T; wk^T; wv^T]
  bf16* woT = (bf16*)alloc((size_t)1024 * 1024 * 2);
  bf16* w1T = (bf16*)alloc((size_t)1024 * 1024 * 2);    // g2-scaled
  bf16* w2T = (bf16*)alloc((size_t)1024 * 1024 * 2);
  bf16* wmsT = (bf16*)alloc((size_t)256 * 1024 * 2);    // g3-scaled [Wmu^T;Wsig^T]
  bf16* hb = (bf16*)alloc((size_t)M * D * 2);           // h1 (resid for Wo)
  bf16* Qb = (bf16*)alloc((size_t)M * D * 2);
  bf16* Kb = (bf16*)alloc((size_t)M * D * 2);
  bf16* Vb = (bf16*)alloc((size_t)M * D * 2);
  bf16* VtG = (bf16*)alloc((size_t)M * D * 2);
  bf16* Cb = (bf16*)alloc((size_t)M * D * 2);           // ctx
  bf16* h2b = (bf16*)alloc((size_t)M * D * 2);
  bf16* hidb = (bf16*)alloc((size_t)M * D * 2);
  bf16* h4b = (bf16*)alloc((size_t)M * D * 2);
  float* rs2 = (float*)alloc((size_t)M * 4);
  float* rm2 = (float*)alloc((size_t)M * 4);
  float* rs3 = (float*)alloc((size_t)M * 4);
  float* rm3 = (float*)alloc((size_t)M * 4);
  // contiguous coef block (zeroed by kernel; lncoef accumulates via atomics)
  float* coefs = (float*)alloc((size_t)2560 * 4);
  float* c1w1 = coefs;           // 1024
  float* c2w1 = coefs + 1024;    // 1024
  float* c1ms = coefs + 2048;    // 256
  float* c2ms = coefs + 2304;    // 256

  dim3 b256(256);
  dim3 b512(512);

  zero_coefs_kernel<<<10, b256, 0, stream>>>(coefs);

  TP8 tp;
  for (int i = 0; i < 8; ++i) tp.gsrc[i] = nullptr;
  tp.src[0] = Wq;   tp.dst[0] = wqkvT;                        tp.ncol[0] = 1024;
  tp.src[1] = Wk;   tp.dst[1] = wqkvT + (size_t)1024 * 1024;  tp.ncol[1] = 1024;
  tp.src[2] = Wv;   tp.dst[2] = wqkvT + (size_t)2048 * 1024;  tp.ncol[2] = 1024;
  tp.src[3] = Wo;   tp.dst[3] = woT;                          tp.ncol[3] = 1024;
  tp.src[4] = W1;   tp.dst[4] = w1T;   tp.ncol[4] = 1024;     tp.gsrc[4] = g2;
  tp.src[5] = W2;   tp.dst[5] = w2T;                          tp.ncol[5] = 1024;
  tp.src[6] = Wmu;  tp.dst[6] = wmsT;  tp.ncol[6] = 128;      tp.gsrc[6] = g3;
  tp.src[7] = Wsig; tp.dst[7] = wmsT + (size_t)128 * 1024;    tp.ncol[7] = 128;
  tp.gsrc[7] = g3;
  transpose8_kernel<<<dim3(16, 16, 8), b256, 0, stream>>>(tp);

  LC3 lc;
  lc.W[0] = W1;   lc.g[0] = g2; lc.be[0] = be2; lc.c1[0] = c1w1;       lc.c2[0] = c2w1;       lc.N[0] = 1024;
  lc.W[1] = Wmu;  lc.g[1] = g3; lc.be[1] = be3; lc.c1[1] = c1ms;       lc.c2[1] = c2ms;       lc.N[1] = 128;
  lc.W[2] = Wsig; lc.g[2] = g3; lc.be[2] = be3; lc.c1[2] = c1ms + 128; lc.c2[2] = c2ms + 128; lc.N[2] = 128;
  lncoef_kernel<<<dim3(16, 3, 16), b256, 0, stream>>>(lc);

  embed_ln_kernel<<<2048, b256, 0, stream>>>(x, emb, g1, be1, hb);  // h1

  // fused QKV: N=3072, outputs routed to Qb/Kb/Vb. 768 blocks = 3 full rounds.
  gemm8_kernel<6><<<dim3(64, 12), b512, 0, stream>>>(hb, wqkvT, bq, bkb, bv,
                                                     Qb, Kb, Vb, nullptr,
                                                     nullptr, nullptr, M, 3072, D);
  vtrans_kernel<<<dim3(256, 8), b256, 0, stream>>>(Vb, VtG);
  attn_kernel<<<dim3(256, 4), b256, 0, stream>>>(Qb, Kb, VtG, Cb);

  // Wo + resid -> h2b
  gemm8_kernel<1><<<dim3(64, 4), b512, 0, stream>>>(Cb, woT, bo, nullptr, nullptr,
                                                    h2b, nullptr, nullptr, hb,
                                                    nullptr, nullptr, M, D, D);
  // LN2 stats (fold applied in W1 epilogue)
  rowstats_kernel<<<2048, b256, 0, stream>>>(h2b, rs2, rm2);
  gemm8_kernel<4><<<dim3(64, 4), b512, 0, stream>>>(h2b, w1T, bf1, c1w1, c2w1,
                                                    hidb, nullptr, nullptr, nullptr,
                                                    rs2, rm2, M, D, D);
  gemm8_kernel<3><<<dim3(64, 4), b512, 0, stream>>>(hidb, w2T, bf2, nullptr, nullptr,
                                                    h4b, nullptr, nullptr, nullptr,
                                                    nullptr, nullptr, M, D, D);
  // LN3 stats (fold applied in musig epilogue) + fused mu/sig/z
  rowstats_kernel<<<2048, b256, 0, stream>>>(h4b, rs3, rm3);
  gemm_musig_z<<<dim3(256), b256, 0, stream>>>(h4b, wmsT, rs3, rm3, c1ms, c2ms,
                                               bmu, bsig, eps, z);
}

// Round 8
// 428.015 us; speedup vs baseline: 1.1871x; 1.0083x over previous
//
#include <hip/hip_runtime.h>
#include <cstdint>

// FirstEncoder: B=16 S=512 D=1024 H=16 L=128 V=32000, DH=64.
// Faithful: raw-reshape head split (head (b,h) = contiguous [512,64] block of
// the flat [8192,1024] buffer), score scale 1/32 (DH/2), FFN residual f+f=2f.
// LN-fold: LN(h;g,be)@W = rstd*(h@(g.W)) + (-rstd*mean)*(g^T W) + be^T W.
// r6: lncoef re-parallelized. r7: kernel-zeroed coefs.
// r8: rowstats folded into Wo/W2 epilogues (atomic row sums, finalized in
//     consumers); lncoef folded into transpose8. 14 -> 11 kernels.

typedef __bf16 bf16;
typedef __bf16 bf16x8 __attribute__((ext_vector_type(8)));
typedef __bf16 bf16x4 __attribute__((ext_vector_type(4)));
typedef float f32x4 __attribute__((ext_vector_type(4)));

#define MFMA16(a, b, c) __builtin_amdgcn_mfma_f32_16x16x32_bf16((a), (b), (c), 0, 0, 0)

#if __has_builtin(__builtin_amdgcn_exp2f)
#define EXP2F(x) __builtin_amdgcn_exp2f(x)
#else
#define EXP2F(x) exp2f(x)
#endif

// async 16B global->LDS (lane i lands at wave-uniform base + i*16)
__device__ __forceinline__ void async16(const bf16* g, bf16* l) {
  __builtin_amdgcn_global_load_lds(
      (const __attribute__((address_space(1))) unsigned int*)g,
      (__attribute__((address_space(3))) unsigned int*)l, 16, 0, 0);
}

// counted waits, pinned against compiler reordering (memory clobber + sched fence)
#define VMWAIT(N)                                        \
  do {                                                   \
    asm volatile("s_waitcnt vmcnt(" #N ")" ::: "memory"); \
    __builtin_amdgcn_sched_barrier(0);                   \
  } while (0)
#define BAR() __builtin_amdgcn_s_barrier()

// ---------------------------------------------------------------------------
// zero 35328 f32 accumulator slots (coefs 2560 + 4x8192 row sums). 138x256.
__global__ __launch_bounds__(256) void zero_coefs_kernel(float* __restrict__ p) {
  p[blockIdx.x * 256 + threadIdx.x] = 0.f;
}

// ---------------------------------------------------------------------------
// 8x fused weight transpose + f32->bf16, optional g-scale, and (when c1dst
// set) fused LN-fold coef accumulation: c1[n] += sum_k g[k]W[k][n],
// c2[n] += sum_k be[k]W[k][n] via per-tile atomics (16 partials per col).
struct TP8 {
  const float* src[8];
  const float* gsrc[8];
  const float* besrc[8];
  bf16* dst[8];
  float* c1dst[8];
  float* c2dst[8];
  int ncol[8];
};
__global__ __launch_bounds__(256) void transpose8_kernel(TP8 p) {
  const int z = blockIdx.z;
  const int N = p.ncol[z];
  const int tk = blockIdx.x * 64, tn = blockIdx.y * 64;
  if (tn >= N) return;
  const float* __restrict__ W = p.src[z];
  bf16* __restrict__ Wt = p.dst[z];
  __shared__ float tile[64][65];
  __shared__ float s1[4][64], s2[4][64];
  const int a = threadIdx.x >> 6, b = threadIdx.x & 63;
#pragma unroll
  for (int i = 0; i < 16; ++i) {
    int k = a + i * 4;
    tile[k][b] = W[(size_t)(tk + k) * N + tn + b];
  }
  __syncthreads();
  const float* gsc = p.gsrc[z];
  const float gv = gsc ? gsc[tk + b] : 1.0f;  // k_glob = tk + b in write loop
#pragma unroll
  for (int i = 0; i < 16; ++i) {
    int n = a + i * 4;
    Wt[(size_t)(tn + n) * 1024 + tk + b] = (bf16)(tile[b][n] * gv);
  }
  if (p.c1dst[z]) {  // block-uniform
    const float* __restrict__ g = p.gsrc[z];
    const float* __restrict__ be = p.besrc[z];
    float a1 = 0.f, a2 = 0.f;
#pragma unroll
    for (int i = 0; i < 16; ++i) {
      const int kk = a * 16 + i;
      const float v = tile[kk][b];
      a1 += g[tk + kk] * v;
      a2 += be[tk + kk] * v;
    }
    s1[a][b] = a1;
    s2[a][b] = a2;
    __syncthreads();
    if (a == 0) {
      atomicAdd(&p.c1dst[z][tn + b], s1[0][b] + s1[1][b] + s1[2][b] + s1[3][b]);
      atomicAdd(&p.c2dst[z][tn + b], s2[0][b] + s2[1][b] + s2[2][b] + s2[3][b]);
    }
  }
}

// ---------------------------------------------------------------------------
// Fused embed (*32 + posenc) + LayerNorm1 -> bf16 h1.
__global__ __launch_bounds__(256) void embed_ln_kernel(const int* __restrict__ x,
                                                       const float* __restrict__ emb,
                                                       const float* __restrict__ g,
                                                       const float* __restrict__ be,
                                                       bf16* __restrict__ obf) {
  const int w = threadIdx.x >> 6, lane = threadIdx.x & 63;
  const int row = blockIdx.x * 4 + w;
  const int s = row & 511;
  const int t = x[row];
  const int c0 = lane * 16;
  const float* er = emb + (size_t)t * 1024 + c0;
  float o[16];
#pragma unroll
  for (int i = 0; i < 4; ++i) {
    const float4 e = *(const float4*)(er + i * 4);
    o[i * 4 + 0] = e.x; o[i * 4 + 1] = e.y; o[i * 4 + 2] = e.z; o[i * 4 + 3] = e.w;
  }
#pragma unroll
  for (int p = 0; p < 8; ++p) {
    const int cc = c0 + 2 * p;
    const float freq = __expf((float)cc * (-9.210340371976184f / 1024.0f));
    const float ang = (float)s * freq;
    o[2 * p] = o[2 * p] * 32.0f + __sinf(ang);
    o[2 * p + 1] = o[2 * p + 1] * 32.0f + __cosf(ang);
  }
  float sm = 0.f, q = 0.f;
#pragma unroll
  for (int j = 0; j < 16; ++j) { sm += o[j]; q += o[j] * o[j]; }
#pragma unroll
  for (int off = 1; off < 64; off <<= 1) {
    sm += __shfl_xor(sm, off);
    q += __shfl_xor(q, off);
  }
  const float mean = sm * (1.0f / 1024.0f);
  const float var = q * (1.0f / 1024.0f) - mean * mean;
  const float rstd = rsqrtf(var + 1e-5f);
  bf16 ob[16];
#pragma unroll
  for (int i = 0; i < 4; ++i) {
    const float4 gv = *(const float4*)(g + c0 + i * 4);
    const float4 bv = *(const float4*)(be + c0 + i * 4);
    const float gvv[4] = {gv.x, gv.y, gv.z, gv.w};
    const float bvv[4] = {bv.x, bv.y, bv.z, bv.w};
#pragma unroll
    for (int j = 0; j < 4; ++j)
      ob[i * 4 + j] = (bf16)((o[i * 4 + j] - mean) * rstd * gvv[j] + bvv[j]);
  }
  bf16* dst = obf + (size_t)row * 1024 + c0;
  *(uint4*)dst = *(const uint4*)&ob[0];
  *(uint4*)(dst + 8) = *(const uint4*)&ob[8];
}

// ---------------------------------------------------------------------------
// 8-phase counted-vmcnt GEMM. BM=128, BN=256, BK=64, 512 thr (8 waves 2Mx4N),
// wave tile 64x64, LDS 96KB (1 block/CU).
// MODE 1: out = acc + b0 + resid; accumulates row sums -> sumOut/sqOut (Wo)
// MODE 3: out = 2*(acc + b0);     accumulates row sums -> sumOut/sqOut (W2)
// MODE 4: out = leaky(rstd*acc + rm*c1 + c2 + b0); rstd/rm from sumIn/sqIn (W1)
// MODE 6: out routed to o0/o1/o2 by n-part (fused QKV)
__device__ __forceinline__ void ld_frags2(const bf16* sm, int rbase, int l15,
                                          int quad, bf16x8 out[2][2]) {
#pragma unroll
  for (int f = 0; f < 2; ++f) {
    const int row = rbase + f * 16 + l15;
    const int rx = row & 7;
#pragma unroll
    for (int h = 0; h < 2; ++h) {
      const int c = (h * 4 + quad) ^ rx;
      out[f][h] = *(const bf16x8*)(sm + (row * 8 + c) * 8);
    }
  }
}

template <int MQ, int NQ>
__device__ __forceinline__ void mma8(const bf16x8 aF[2][2], const bf16x8 bF[2][2],
                                     f32x4 acc[4][4]) {
  __builtin_amdgcn_s_setprio(1);
#pragma unroll
  for (int h = 0; h < 2; ++h)
#pragma unroll
    for (int m2 = 0; m2 < 2; ++m2)
#pragma unroll
      for (int n2 = 0; n2 < 2; ++n2)
        acc[MQ * 2 + m2][NQ * 2 + n2] =
            MFMA16(aF[m2][h], bF[n2][h], acc[MQ * 2 + m2][NQ * 2 + n2]);
  __builtin_amdgcn_s_setprio(0);
}

template <int MODE>
__global__ __launch_bounds__(512, 2) void gemm8_kernel(
    const bf16* __restrict__ A, const bf16* __restrict__ Bt,
    const float* __restrict__ b0f, const float* __restrict__ b1f,
    const float* __restrict__ b2f,
    bf16* __restrict__ o0, bf16* __restrict__ o1, bf16* __restrict__ o2,
    const bf16* __restrict__ residb,
    const float* __restrict__ sumIn, const float* __restrict__ sqIn,
    float* __restrict__ sumOut, float* __restrict__ sqOut,
    int M, int N, int K) {
  (void)M;
  __shared__ __attribute__((aligned(16))) bf16 Asm[2][128 * 64];
  __shared__ __attribute__((aligned(16))) bf16 Bsm[2][256 * 64];
  const int tid = threadIdx.x;
  const int wv = tid >> 6, lane = tid & 63;
  const int quad = lane >> 4, l15 = lane & 15;
  const int wm = wv & 1, wn = wv >> 1;
  const int m0 = blockIdx.x * 128, n0 = blockIdx.y * 256;

  f32x4 acc[4][4];
#pragma unroll
  for (int i = 0; i < 4; ++i)
#pragma unroll
    for (int j = 0; j < 4; ++j) acc[i][j] = {0.f, 0.f, 0.f, 0.f};

  size_t aoff[2], boff[2];
  int slds[2];
#pragma unroll
  for (int i = 0; i < 2; ++i) {
    const int s = tid + i * 512;
    const int r = s >> 3, c = (s & 7) ^ (r & 7);
    aoff[i] = (size_t)(m0 + r) * K + c * 8;
    boff[i] = (size_t)(n0 + r) * K + c * 8;
    slds[i] = s * 8;
  }
  auto stageA = [&](int buf, int t) {
#pragma unroll
    for (int i = 0; i < 2; ++i) async16(A + aoff[i] + t * 64, &Asm[buf][slds[i]]);
  };
  auto stageB = [&](int buf, int hh, int t) {
    const size_t ho = (size_t)hh * 128 * K;
    const int hl = hh * 8192;
#pragma unroll
    for (int i = 0; i < 2; ++i)
      async16(Bt + boff[i] + ho + t * 64, &Bsm[buf][hl + slds[i]]);
  };

  stageB(0, 0, 0); stageB(0, 1, 0); stageA(0, 0);
  stageB(1, 0, 1); stageB(1, 1, 1); stageA(1, 1);
  VMWAIT(6);
  BAR();

  bf16x8 aF[2][2], bF0[2][2], bF1[2][2];
  const int am0 = wm * 64, bn0 = wn * 64;

  auto phases = [&](int ne, int no, bool hn) {
    ld_frags2(&Asm[0][0], am0, l15, quad, aF);
    ld_frags2(&Bsm[0][0], bn0, l15, quad, bF0);
    BAR();
    mma8<0, 0>(aF, bF0, acc);
    BAR();
    ld_frags2(&Bsm[0][0], bn0 + 32, l15, quad, bF1);
    BAR();
    mma8<0, 1>(aF, bF1, acc);
    BAR();
    ld_frags2(&Asm[0][0], am0 + 32, l15, quad, aF);
    if (hn) stageB(0, 0, ne);
    BAR();
    mma8<1, 1>(aF, bF1, acc);
    BAR();
    if (hn) stageB(0, 1, ne);
    BAR();
    mma8<1, 0>(aF, bF0, acc);
    if (hn) { VMWAIT(4); } else { VMWAIT(0); }
    BAR();
    ld_frags2(&Asm[1][0], am0, l15, quad, aF);
    ld_frags2(&Bsm[1][0], bn0, l15, quad, bF0);
    if (hn) stageA(0, ne);
    BAR();
    mma8<0, 0>(aF, bF0, acc);
    BAR();
    ld_frags2(&Bsm[1][0], bn0 + 32, l15, quad, bF1);
    BAR();
    mma8<0, 1>(aF, bF1, acc);
    BAR();
    ld_frags2(&Asm[1][0], am0 + 32, l15, quad, aF);
    if (hn) stageB(1, 0, no);
    BAR();
    mma8<1, 1>(aF, bF1, acc);
    BAR();
    if (hn) { stageB(1, 1, no); stageA(1, no); }
    BAR();
    mma8<1, 0>(aF, bF0, acc);
    if (hn) { VMWAIT(6); }
    BAR();
  };

  const int nIter = K >> 7;
  for (int it = 0; it + 1 < nIter; ++it) phases(2 * it + 2, 2 * it + 3, true);
  phases(0, 0, false);

  const int part = (MODE == 6) ? ((int)blockIdx.y >> 2) : 0;
  bf16* ob = o0;
  const float* bp = b0f;
  if constexpr (MODE == 6) {
    ob = (part == 0) ? o0 : (part == 1 ? o1 : o2);
    bp = (part == 0) ? b0f : (part == 1 ? b1f : b2f);
  }

  // hoist per-ni column constants
  float bvv[4], c1v[4], c2v[4];
  int cls[4];
#pragma unroll
  for (int ni = 0; ni < 4; ++ni) {
    const int col = n0 + wn * 64 + ni * 16 + l15;
    const int cl = (MODE == 6) ? (col - part * 1024) : col;
    cls[ni] = cl;
    bvv[ni] = bp[cl];
    if constexpr (MODE == 4) { c1v[ni] = b1f[col]; c2v[ni] = b2f[col]; }
    else { c1v[ni] = 0.f; c2v[ni] = 0.f; }
  }

#pragma unroll
  for (int mi = 0; mi < 4; ++mi) {
#pragma unroll
    for (int r = 0; r < 4; ++r) {
      const int row = m0 + wm * 64 + mi * 16 + quad * 4 + r;
      float rstd = 0.f, rmean = 0.f;
      if constexpr (MODE == 4) {
        const float s = sumIn[row], q = sqIn[row];
        const float mean = s * (1.0f / 1024.0f);
        const float var = q * (1.0f / 1024.0f) - mean * mean;
        rstd = rsqrtf(var + 1e-5f);
        rmean = -rstd * mean;
      }
      float ps = 0.f, pq = 0.f;
#pragma unroll
      for (int ni = 0; ni < 4; ++ni) {
        const int col = n0 + wn * 64 + ni * 16 + l15;
        const float a = acc[mi][ni][r];
        if constexpr (MODE == 1) {
          const size_t idx = (size_t)row * N + col;
          const float v = a + bvv[ni] + (float)residb[idx];
          o0[idx] = (bf16)v;
          ps += v; pq += v * v;
        } else if constexpr (MODE == 4) {
          const float v = rstd * a + rmean * c1v[ni] + c2v[ni] + bvv[ni];
          o0[(size_t)row * N + col] = (bf16)(v > 0.f ? v : 0.01f * v);
        } else if constexpr (MODE == 3) {
          const float v = 2.0f * (a + bvv[ni]);
          o0[(size_t)row * N + col] = (bf16)v;
          ps += v; pq += v * v;
        } else {  // MODE 6
          ob[(size_t)row * 1024 + cls[ni]] = (bf16)(a + bvv[ni]);
        }
      }
      if constexpr (MODE == 1 || MODE == 3) {
        // reduce across the 16-lane quad group (xor<16 stays in-group)
        ps += __shfl_xor(ps, 1); pq += __shfl_xor(pq, 1);
        ps += __shfl_xor(ps, 2); pq += __shfl_xor(pq, 2);
        ps += __shfl_xor(ps, 4); pq += __shfl_xor(pq, 4);
        ps += __shfl_xor(ps, 8); pq += __shfl_xor(pq, 8);
        if (l15 == 0) {
          atomicAdd(&sumOut[row], ps);
          atomicAdd(&sqOut[row], pq);
        }
      }
    }
  }
}

// ---------------------------------------------------------------------------
// Fused mu|sig GEMM + reparameterization; LN-fold stats finalized inline from
// sum/sq accumulators (produced by W2 epilogue).
// Tile 32 rows x 256 cols, grid (256), 256 thr (4 waves).
__global__ __launch_bounds__(256) void gemm_musig_z(
    const bf16* __restrict__ A, const bf16* __restrict__ Bt,
    const float* __restrict__ sumP, const float* __restrict__ sqP,
    const float* __restrict__ c1, const float* __restrict__ c2,
    const float* __restrict__ bmu, const float* __restrict__ bsig,
    const float* __restrict__ eps, float* __restrict__ z) {
  __shared__ __attribute__((aligned(16))) bf16 Asm[2][32 * 64];
  __shared__ __attribute__((aligned(16))) bf16 Bsm[2][256 * 64];
  const int tid = threadIdx.x;
  const int wv = tid >> 6, lane = tid & 63;
  const int quad = lane >> 4, l15 = lane & 15;
  const int m0 = blockIdx.x * 32;

  f32x4 acc[2][4];
#pragma unroll
  for (int i = 0; i < 2; ++i)
#pragma unroll
    for (int j = 0; j < 4; ++j) acc[i][j] = {0.f, 0.f, 0.f, 0.f};

  const bf16* Ag;
  int as_;
  {
    const int s = tid;
    const int r = s >> 3, c = (s & 7) ^ (r & 7);
    Ag = A + (size_t)(m0 + r) * 1024 + c * 8;
    as_ = s * 8;
  }
  const bf16* Bg[8];
  int bs_[8];
#pragma unroll
  for (int i = 0; i < 8; ++i) {
    const int s = tid + i * 256;
    const int r = s >> 3, c = (s & 7) ^ (r & 7);
    Bg[i] = Bt + (size_t)r * 1024 + c * 8;
    bs_[i] = s * 8;
  }

  async16(Ag, &Asm[0][as_]);
#pragma unroll
  for (int i = 0; i < 8; ++i) async16(Bg[i], &Bsm[0][bs_[i]]);
  __syncthreads();

  for (int k = 0; k < 16; ++k) {
    const int cur = k & 1, nxt = cur ^ 1;
    bf16x8 af[2][2], bfr[4][2];
#pragma unroll
    for (int mi = 0; mi < 2; ++mi) {
      const int row = mi * 16 + l15;
#pragma unroll
      for (int h = 0; h < 2; ++h) {
        const int pos = (h * 4 + quad) ^ (row & 7);
        af[mi][h] = *(const bf16x8*)(&Asm[cur][(row * 8 + pos) * 8]);
      }
    }
#pragma unroll
    for (int ni = 0; ni < 4; ++ni) {
      const int nr = (ni < 2 ? wv * 32 + ni * 16 : 128 + wv * 32 + (ni - 2) * 16) + l15;
#pragma unroll
      for (int h = 0; h < 2; ++h) {
        const int pos = (h * 4 + quad) ^ (nr & 7);
        bfr[ni][h] = *(const bf16x8*)(&Bsm[cur][(nr * 8 + pos) * 8]);
      }
    }
    if (k + 1 < 16) {
      const int ko = (k + 1) * 64;
      async16(Ag + ko, &Asm[nxt][as_]);
#pragma unroll
      for (int i = 0; i < 8; ++i) async16(Bg[i] + ko, &Bsm[nxt][bs_[i]]);
    }
#pragma unroll
    for (int h = 0; h < 2; ++h)
#pragma unroll
      for (int mi = 0; mi < 2; ++mi)
#pragma unroll
        for (int ni = 0; ni < 4; ++ni)
          acc[mi][ni] = MFMA16(af[mi][h], bfr[ni][h], acc[mi][ni]);
    __syncthreads();
  }

#pragma unroll
  for (int mi = 0; mi < 2; ++mi) {
#pragma unroll
    for (int r = 0; r < 4; ++r) {
      const int row = m0 + mi * 16 + quad * 4 + r;
      const float s = sumP[row], q = sqP[row];
      const float mean = s * (1.0f / 1024.0f);
      const float var = q * (1.0f / 1024.0f) - mean * mean;
      const float rs = rsqrtf(var + 1e-5f);
      const float rm = -rs * mean;
#pragma unroll
      for (int cg = 0; cg < 2; ++cg) {
        const int cmu = wv * 32 + cg * 16 + l15;
        const int csg = 128 + cmu;
        const float mu = rs * acc[mi][cg][r] + rm * c1[cmu] + c2[cmu] + bmu[cmu];
        const float sg = rs * acc[mi][2 + cg][r] + rm * c1[csg] + c2[csg] + bsig[cmu];
        z[(size_t)row * 128 + cmu] = mu + __expf(sg) * eps[(size_t)row * 128 + cmu];
      }
    }
  }
}

// ---------------------------------------------------------------------------
// V transpose per head: Vb flat [256 bh][512 kv][64 d] -> VtG [256 bh][64 d][512 kv]
__global__ __launch_bounds__(256) void vtrans_kernel(const bf16* __restrict__ Vb,
                                                     bf16* __restrict__ VtG) {
  __shared__ float t[64][65];
  const int bh = blockIdx.x, kt = blockIdx.y;
  const int tid = threadIdx.x;
  const bf16* src = Vb + (size_t)bh * 32768 + (size_t)kt * 4096;
#pragma unroll
  for (int i = 0; i < 2; ++i) {
    int s = i * 256 + tid;
    int r = s >> 3, c = (s & 7) * 8;
    bf16x8 v = *(const bf16x8*)(src + (size_t)s * 8);
#pragma unroll
    for (int j = 0; j < 8; ++j) t[r][c + j] = (float)v[j];
  }
  __syncthreads();
  bf16* dst = VtG + (size_t)bh * 32768 + kt * 64;
#pragma unroll
  for (int i = 0; i < 2; ++i) {
    int s = i * 256 + tid;
    int d = s >> 3, kc = (s & 7) * 8;
    bf16 tmp[8];
#pragma unroll
    for (int j = 0; j < 8; ++j) tmp[j] = (bf16)t[kc + j][d];
    *(uint4*)(dst + (size_t)d * 512 + kc) = *(const uint4*)tmp;
  }
}

// ---------------------------------------------------------------------------
// Flash-style attention. grid (256 bh, 4 qblk), 256 threads (4 waves).
// No-max softmax (|score/32| small): p = exp2(score * log2e/32) via Q prescale.
__global__ __launch_bounds__(256) void attn_kernel(const bf16* __restrict__ Qg,
                                                   const bf16* __restrict__ Kg,
                                                   const bf16* __restrict__ Vt,
                                                   bf16* __restrict__ ctx) {
  __shared__ __attribute__((aligned(16))) bf16 Ksm[128 * 64];
  __shared__ __attribute__((aligned(16))) bf16 Vsm[64 * 128];
  __shared__ __attribute__((aligned(16))) bf16 Psm[4][16 * 128];
  const int tid = threadIdx.x;
  const int w = tid >> 6, lane = tid & 63;
  const int quad = lane >> 4, l15 = lane & 15;
  const int bh = blockIdx.x;
  const size_t base = (size_t)bh * 32768;
  const bf16* Vth = Vt + base;
  const int qbase = blockIdx.y * 128 + w * 32;
  const f32x4 fz = {0.f, 0.f, 0.f, 0.f};

  bf16x8 a[2][2];
#pragma unroll
  for (int qt = 0; qt < 2; ++qt)
#pragma unroll
    for (int hf = 0; hf < 2; ++hf) {
      bf16x8 tq = *(const bf16x8*)(Qg + base +
                   (size_t)(qbase + qt * 16 + l15) * 64 + hf * 32 + quad * 8);
#pragma unroll
      for (int e = 0; e < 8; ++e) tq[e] = (bf16)((float)tq[e] * 0.045111758f);
      a[qt][hf] = tq;
    }

  f32x4 o[2][4];
  float l_i[2][4];
#pragma unroll
  for (int qt = 0; qt < 2; ++qt)
#pragma unroll
    for (int i = 0; i < 4; ++i) { o[qt][i] = fz; l_i[qt][i] = 0.f; }

  for (int kv0 = 0; kv0 < 512; kv0 += 128) {
#pragma unroll
    for (int i = 0; i < 4; ++i) {
      int s = i * 256 + tid;
      int r = s >> 3, c = (s & 7) ^ (r & 7);
      async16(Kg + base + (size_t)(kv0 + r) * 64 + c * 8, &Ksm[s * 8]);
    }
#pragma unroll
    for (int i = 0; i < 4; ++i) {
      int s = i * 256 + tid;
      int d = s >> 4, cs = s & 15;
      int c = (cs & 8) | ((cs & 7) ^ (d & 7));
      async16(Vth + (size_t)d * 512 + kv0 + c * 8, &Vsm[s * 8]);
    }
    __syncthreads();

    f32x4 sc[2][8];
#pragma unroll
    for (int j = 0; j < 8; ++j) {
      const int n = j * 16 + l15;
      const bf16x8 k0 = *(const bf16x8*)(&Ksm[(n * 8 + (quad ^ (n & 7))) * 8]);
      const bf16x8 k1 = *(const bf16x8*)(&Ksm[(n * 8 + ((4 + quad) ^ (n & 7))) * 8]);
      sc[0][j] = MFMA16(a[0][0], k0, fz);
      sc[0][j] = MFMA16(a[0][1], k1, sc[0][j]);
      sc[1][j] = MFMA16(a[1][0], k0, fz);
      sc[1][j] = MFMA16(a[1][1], k1, sc[1][j]);
    }

    bf16* ps = &Psm[w][0];
#pragma unroll
    for (int qt = 0; qt < 2; ++qt) {
#pragma unroll
      for (int r = 0; r < 4; ++r) {
        const int prow = quad * 4 + r;
        float sum = 0.f;
#pragma unroll
        for (int j = 0; j < 8; ++j) {
          const float p = EXP2F(sc[qt][j][r]);
          sum += p;
          const int col = j * 16 + l15;
          const int cc = col >> 3;
          const int ccs = (cc & 8) | ((cc & 7) ^ (prow & 7));
          ps[prow * 128 + ccs * 8 + (col & 7)] = (bf16)p;
        }
        l_i[qt][r] += sum;
      }
#pragma unroll
      for (int c32 = 0; c32 < 4; ++c32) {
        const int pc = c32 * 4 + quad;
        const int pcs = (pc & 8) | ((pc & 7) ^ (l15 & 7));
        const bf16x8 pf = *(const bf16x8*)(ps + l15 * 128 + pcs * 8);
#pragma unroll
        for (int ni = 0; ni < 4; ++ni) {
          const int d = ni * 16 + l15;
          const int vcs = (pc & 8) | ((pc & 7) ^ (d & 7));
          const bf16x8 vf = *(const bf16x8*)(&Vsm[(d * 16 + vcs) * 8]);
          o[qt][ni] = MFMA16(pf, vf, o[qt][ni]);
        }
      }
    }
    __syncthreads();
  }

#pragma unroll
  for (int qt = 0; qt < 2; ++qt) {
#pragma unroll
    for (int r = 0; r < 4; ++r) {
      float l = l_i[qt][r];
      l += __shfl_xor(l, 1);
      l += __shfl_xor(l, 2);
      l += __shfl_xor(l, 4);
      l += __shfl_xor(l, 8);
      const float inv = 1.0f / l;
#pragma unroll
      for (int ni = 0; ni < 4; ++ni)
        ctx[base + (size_t)(qbase + qt * 16 + quad * 4 + r) * 64 + ni * 16 + l15]
            = (bf16)(o[qt][ni][r] * inv);
    }
  }
}

// ---------------------------------------------------------------------------
extern "C" void kernel_launch(void* const* d_in, const int* in_sizes, int n_in,
                              void* d_out, int out_size, void* d_ws, size_t ws_size,
                              hipStream_t stream) {
  (void)in_sizes; (void)n_in; (void)out_size; (void)ws_size;
  const int* x = (const int*)d_in[0];
  const float* emb = (const float*)d_in[1];
  const float* Wq = (const float*)d_in[2];
  const float* bq = (const float*)d_in[3];
  const float* Wk = (const float*)d_in[4];
  const float* bkb = (const float*)d_in[5];
  const float* Wv = (const float*)d_in[6];
  const float* bv = (const float*)d_in[7];
  const float* Wo = (const float*)d_in[8];
  const float* bo = (const float*)d_in[9];
  const float* g1 = (const float*)d_in[10];
  const float* be1 = (const float*)d_in[11];
  const float* W1 = (const float*)d_in[12];
  const float* bf1 = (const float*)d_in[13];
  const float* W2 = (const float*)d_in[14];
  const float* bf2 = (const float*)d_in[15];
  const float* g2 = (const float*)d_in[16];
  const float* be2 = (const float*)d_in[17];
  const float* g3 = (const float*)d_in[18];
  const float* be3 = (const float*)d_in[19];
  const float* Wmu = (const float*)d_in[20];
  const float* bmu = (const float*)d_in[21];
  const float* Wsig = (const float*)d_in[22];
  const float* bsig = (const float*)d_in[23];
  const float* eps = (const float*)d_in[24];
  float* z = (float*)d_out;

  const int M = 8192, D = 1024;
  char* ws = (char*)d_ws;
  size_t off = 0;
  auto alloc = [&](size_t b) {
    char* p = ws + off;
    off += (b + 255) & ~(size_t)255;
    return p;
  };
  bf16* wqkvT = (bf16*)alloc((size_t)3072 * 1024 * 2);  // [wq^T; wk^T; wv^T]
  bf16* woT = (bf16*)alloc((size_t)1024 * 1024 * 2);
  bf16* w1T = (bf16*)alloc((size_t)1024 * 1024 * 2);    // g2-scaled
  bf16* w2T = (bf16*)alloc((size_t)1024 * 1024 * 2);
  bf16* wmsT = (bf16*)alloc((size_t)256 * 1024 * 2);    // g3-scaled [Wmu^T;Wsig^T]
  bf16* hb = (bf16*)alloc((size_t)M * D * 2);           // h1 (resid for Wo)
  bf16* Qb = (bf16*)alloc((size_t)M * D * 2);
  bf16* Kb = (bf16*)alloc((size_t)M * D * 2);
  bf16* Vb = (bf16*)alloc((size_t)M * D * 2);
  bf16* VtG = (bf16*)alloc((size_t)M * D * 2);
  bf16* Cb = (bf16*)alloc((size_t)M * D * 2);           // ctx
  bf16* h2b = (bf16*)alloc((size_t)M * D * 2);
  bf16* hidb = (bf16*)alloc((size_t)M * D * 2);
  bf16* h4b = (bf16*)alloc((size_t)M * D * 2);
  // contiguous accumulator block (zeroed by kernel): coefs + row sums
  float* coefs = (float*)alloc((size_t)35328 * 4);
  float* c1w1 = coefs;            // 1024
  float* c2w1 = coefs + 1024;     // 1024
  float* c1ms = coefs + 2048;     // 256
  float* c2ms = coefs + 2304;     // 256
  float* sum2 = coefs + 2560;     // 8192
  float* sq2 = coefs + 10752;     // 8192
  float* sum3 = coefs + 18944;    // 8192
  float* sq3 = coefs + 27136;     // 8192 (end 35328)

  dim3 b256(256);
  dim3 b512(512);

  zero_coefs_kernel<<<138, b256, 0, stream>>>(coefs);

  TP8 tp;
  for (int i = 0; i < 8; ++i) {
    tp.gsrc[i] = nullptr; tp.besrc[i] = nullptr;
    tp.c1dst[i] = nullptr; tp.c2dst[i] = nullptr;
  }
  tp.src[0] = Wq;   tp.dst[0] = wqkvT;                        tp.ncol[0] = 1024;
  tp.src[1] = Wk;   tp.dst[1] = wqkvT + (size_t)1024 * 1024;  tp.ncol[1] = 1024;
  tp.src[2] = Wv;   tp.dst[2] = wqkvT + (size_t)2048 * 1024;  tp.ncol[2] = 1024;
  tp.src[3] = Wo;   tp.dst[3] = woT;                          tp.ncol[3] = 1024;
  tp.src[4] = W1;   tp.dst[4] = w1T;   tp.ncol[4] = 1024;
  tp.gsrc[4] = g2;  tp.besrc[4] = be2; tp.c1dst[4] = c1w1;    tp.c2dst[4] = c2w1;
  tp.src[5] = W2;   tp.dst[5] = w2T;                          tp.ncol[5] = 1024;
  tp.src[6] = Wmu;  tp.dst[6] = wmsT;  tp.ncol[6] = 128;
  tp.gsrc[6] = g3;  tp.besrc[6] = be3; tp.c1dst[6] = c1ms;    tp.c2dst[6] = c2ms;
  tp.src[7] = Wsig; tp.dst[7] = wmsT + (size_t)128 * 1024;    tp.ncol[7] = 128;
  tp.gsrc[7] = g3;  tp.besrc[7] = be3; tp.c1dst[7] = c1ms + 128; tp.c2dst[7] = c2ms + 128;
  transpose8_kernel<<<dim3(16, 16, 8), b256, 0, stream>>>(tp);

  embed_ln_kernel<<<2048, b256, 0, stream>>>(x, emb, g1, be1, hb);  // h1

  // fused QKV: N=3072, outputs routed to Qb/Kb/Vb. 768 blocks = 3 full rounds.
  gemm8_kernel<6><<<dim3(64, 12), b512, 0, stream>>>(hb, wqkvT, bq, bkb, bv,
                                                     Qb, Kb, Vb, nullptr,
                                                     nullptr, nullptr, nullptr,
                                                     nullptr, M, 3072, D);
  vtrans_kernel<<<dim3(256, 8), b256, 0, stream>>>(Vb, VtG);
  attn_kernel<<<dim3(256, 4), b256, 0, stream>>>(Qb, Kb, VtG, Cb);

  // Wo + resid -> h2b; accumulates LN2 row sums
  gemm8_kernel<1><<<dim3(64, 4), b512, 0, stream>>>(Cb, woT, bo, nullptr, nullptr,
                                                    h2b, nullptr, nullptr, hb,
                                                    nullptr, nullptr, sum2, sq2,
                                                    M, D, D);
  // W1 with LN2-fold finalized inline from sums
  gemm8_kernel<4><<<dim3(64, 4), b512, 0, stream>>>(h2b, w1T, bf1, c1w1, c2w1,
                                                    hidb, nullptr, nullptr, nullptr,
                                                    sum2, sq2, nullptr, nullptr,
                                                    M, D, D);
  // W2 (f+f) -> h4b; accumulates LN3 row sums
  gemm8_kernel<3><<<dim3(64, 4), b512, 0, stream>>>(hidb, w2T, bf2, nullptr, nullptr,
                                                    h4b, nullptr, nullptr, nullptr,
                                                    nullptr, nullptr, sum3, sq3,
                                                    M, D, D);
  // fused mu/sig/z with LN3-fold finalized inline
  gemm_musig_z<<<dim3(256), b256, 0, stream>>>(h4b, wmsT, sum3, sq3, c1ms, c2ms,
                                               bmu, bsig, eps, z);
}

// Round 9
// 425.557 us; speedup vs baseline: 1.1940x; 1.0058x over previous
//
#include <hip/hip_runtime.h>
#include <cstdint>

// FirstEncoder: B=16 S=512 D=1024 H=16 L=128 V=32000, DH=64.
// Faithful: raw-reshape head split (head (b,h) = contiguous [512,64] block of
// the flat [8192,1024] buffer), score scale 1/32 (DH/2), FFN residual f+f=2f.
// LN-fold: LN(h;g,be)@W = rstd*(h@(g.W)) + (-rstd*mean)*(g^T W) + be^T W.
// r6: lncoef re-parallelized. r7: kernel-zeroed coefs. r8: rowstats folded
// into Wo/W2 epilogues; lncoef folded into transpose8.
// r9: Q-prescale (log2e/32) folded into QKV epilogue (better numerics, attn
//     VALU trim); zero_coefs merged into embed_ln launch. 11 -> 10 kernels.

typedef __bf16 bf16;
typedef __bf16 bf16x8 __attribute__((ext_vector_type(8)));
typedef __bf16 bf16x4 __attribute__((ext_vector_type(4)));
typedef float f32x4 __attribute__((ext_vector_type(4)));

#define MFMA16(a, b, c) __builtin_amdgcn_mfma_f32_16x16x32_bf16((a), (b), (c), 0, 0, 0)

#if __has_builtin(__builtin_amdgcn_exp2f)
#define EXP2F(x) __builtin_amdgcn_exp2f(x)
#else
#define EXP2F(x) exp2f(x)
#endif

// async 16B global->LDS (lane i lands at wave-uniform base + i*16)
__device__ __forceinline__ void async16(const bf16* g, bf16* l) {
  __builtin_amdgcn_global_load_lds(
      (const __attribute__((address_space(1))) unsigned int*)g,
      (__attribute__((address_space(3))) unsigned int*)l, 16, 0, 0);
}

// counted waits, pinned against compiler reordering (memory clobber + sched fence)
#define VMWAIT(N)                                        \
  do {                                                   \
    asm volatile("s_waitcnt vmcnt(" #N ")" ::: "memory"); \
    __builtin_amdgcn_sched_barrier(0);                   \
  } while (0)
#define BAR() __builtin_amdgcn_s_barrier()

// ---------------------------------------------------------------------------
// 8x fused weight transpose + f32->bf16, optional g-scale, and (when c1dst
// set) fused LN-fold coef accumulation: c1[n] += sum_k g[k]W[k][n],
// c2[n] += sum_k be[k]W[k][n] via per-tile atomics (16 partials per col).
struct TP8 {
  const float* src[8];
  const float* gsrc[8];
  const float* besrc[8];
  bf16* dst[8];
  float* c1dst[8];
  float* c2dst[8];
  int ncol[8];
};
__global__ __launch_bounds__(256) void transpose8_kernel(TP8 p) {
  const int z = blockIdx.z;
  const int N = p.ncol[z];
  const int tk = blockIdx.x * 64, tn = blockIdx.y * 64;
  if (tn >= N) return;
  const float* __restrict__ W = p.src[z];
  bf16* __restrict__ Wt = p.dst[z];
  __shared__ float tile[64][65];
  __shared__ float s1[4][64], s2[4][64];
  const int a = threadIdx.x >> 6, b = threadIdx.x & 63;
#pragma unroll
  for (int i = 0; i < 16; ++i) {
    int k = a + i * 4;
    tile[k][b] = W[(size_t)(tk + k) * N + tn + b];
  }
  __syncthreads();
  const float* gsc = p.gsrc[z];
  const float gv = gsc ? gsc[tk + b] : 1.0f;  // k_glob = tk + b in write loop
#pragma unroll
  for (int i = 0; i < 16; ++i) {
    int n = a + i * 4;
    Wt[(size_t)(tn + n) * 1024 + tk + b] = (bf16)(tile[b][n] * gv);
  }
  if (p.c1dst[z]) {  // block-uniform
    const float* __restrict__ g = p.gsrc[z];
    const float* __restrict__ be = p.besrc[z];
    float a1 = 0.f, a2 = 0.f;
#pragma unroll
    for (int i = 0; i < 16; ++i) {
      const int kk = a * 16 + i;
      const float v = tile[kk][b];
      a1 += g[tk + kk] * v;
      a2 += be[tk + kk] * v;
    }
    s1[a][b] = a1;
    s2[a][b] = a2;
    __syncthreads();
    if (a == 0) {
      atomicAdd(&p.c1dst[z][tn + b], s1[0][b] + s1[1][b] + s1[2][b] + s1[3][b]);
      atomicAdd(&p.c2dst[z][tn + b], s2[0][b] + s2[1][b] + s2[2][b] + s2[3][b]);
    }
  }
}

// ---------------------------------------------------------------------------
// Fused embed (*32 + posenc) + LayerNorm1 -> bf16 h1; extra blocks (>=2048)
// zero the 35328-f32 accumulator region (coefs + row sums). Runs FIRST.
__global__ __launch_bounds__(256) void embed_ln_kernel(const int* __restrict__ x,
                                                       const float* __restrict__ emb,
                                                       const float* __restrict__ g,
                                                       const float* __restrict__ be,
                                                       bf16* __restrict__ obf,
                                                       float* __restrict__ zf) {
  if (blockIdx.x >= 2048) {
    zf[(blockIdx.x - 2048) * 256 + threadIdx.x] = 0.f;
    return;
  }
  const int w = threadIdx.x >> 6, lane = threadIdx.x & 63;
  const int row = blockIdx.x * 4 + w;
  const int s = row & 511;
  const int t = x[row];
  const int c0 = lane * 16;
  const float* er = emb + (size_t)t * 1024 + c0;
  float o[16];
#pragma unroll
  for (int i = 0; i < 4; ++i) {
    const float4 e = *(const float4*)(er + i * 4);
    o[i * 4 + 0] = e.x; o[i * 4 + 1] = e.y; o[i * 4 + 2] = e.z; o[i * 4 + 3] = e.w;
  }
#pragma unroll
  for (int p = 0; p < 8; ++p) {
    const int cc = c0 + 2 * p;
    const float freq = __expf((float)cc * (-9.210340371976184f / 1024.0f));
    const float ang = (float)s * freq;
    o[2 * p] = o[2 * p] * 32.0f + __sinf(ang);
    o[2 * p + 1] = o[2 * p + 1] * 32.0f + __cosf(ang);
  }
  float sm = 0.f, q = 0.f;
#pragma unroll
  for (int j = 0; j < 16; ++j) { sm += o[j]; q += o[j] * o[j]; }
#pragma unroll
  for (int off = 1; off < 64; off <<= 1) {
    sm += __shfl_xor(sm, off);
    q += __shfl_xor(q, off);
  }
  const float mean = sm * (1.0f / 1024.0f);
  const float var = q * (1.0f / 1024.0f) - mean * mean;
  const float rstd = rsqrtf(var + 1e-5f);
  bf16 ob[16];
#pragma unroll
  for (int i = 0; i < 4; ++i) {
    const float4 gv = *(const float4*)(g + c0 + i * 4);
    const float4 bv = *(const float4*)(be + c0 + i * 4);
    const float gvv[4] = {gv.x, gv.y, gv.z, gv.w};
    const float bvv[4] = {bv.x, bv.y, bv.z, bv.w};
#pragma unroll
    for (int j = 0; j < 4; ++j)
      ob[i * 4 + j] = (bf16)((o[i * 4 + j] - mean) * rstd * gvv[j] + bvv[j]);
  }
  bf16* dst = obf + (size_t)row * 1024 + c0;
  *(uint4*)dst = *(const uint4*)&ob[0];
  *(uint4*)(dst + 8) = *(const uint4*)&ob[8];
}

// ---------------------------------------------------------------------------
// 8-phase counted-vmcnt GEMM. BM=128, BN=256, BK=64, 512 thr (8 waves 2Mx4N),
// wave tile 64x64, LDS 96KB (1 block/CU).
// MODE 1: out = acc + b0 + resid; accumulates row sums -> sumOut/sqOut (Wo)
// MODE 3: out = 2*(acc + b0);     accumulates row sums -> sumOut/sqOut (W2)
// MODE 4: out = leaky(rstd*acc + rm*c1 + c2 + b0); rstd/rm from sumIn/sqIn (W1)
// MODE 6: out routed to o0/o1/o2 by n-part (fused QKV); Q (part 0) prescaled
//         by log2e/32 so attn's exp2 softmax needs no per-frag scaling.
__device__ __forceinline__ void ld_frags2(const bf16* sm, int rbase, int l15,
                                          int quad, bf16x8 out[2][2]) {
#pragma unroll
  for (int f = 0; f < 2; ++f) {
    const int row = rbase + f * 16 + l15;
    const int rx = row & 7;
#pragma unroll
    for (int h = 0; h < 2; ++h) {
      const int c = (h * 4 + quad) ^ rx;
      out[f][h] = *(const bf16x8*)(sm + (row * 8 + c) * 8);
    }
  }
}

template <int MQ, int NQ>
__device__ __forceinline__ void mma8(const bf16x8 aF[2][2], const bf16x8 bF[2][2],
                                     f32x4 acc[4][4]) {
  __builtin_amdgcn_s_setprio(1);
#pragma unroll
  for (int h = 0; h < 2; ++h)
#pragma unroll
    for (int m2 = 0; m2 < 2; ++m2)
#pragma unroll
      for (int n2 = 0; n2 < 2; ++n2)
        acc[MQ * 2 + m2][NQ * 2 + n2] =
            MFMA16(aF[m2][h], bF[n2][h], acc[MQ * 2 + m2][NQ * 2 + n2]);
  __builtin_amdgcn_s_setprio(0);
}

template <int MODE>
__global__ __launch_bounds__(512, 2) void gemm8_kernel(
    const bf16* __restrict__ A, const bf16* __restrict__ Bt,
    const float* __restrict__ b0f, const float* __restrict__ b1f,
    const float* __restrict__ b2f,
    bf16* __restrict__ o0, bf16* __restrict__ o1, bf16* __restrict__ o2,
    const bf16* __restrict__ residb,
    const float* __restrict__ sumIn, const float* __restrict__ sqIn,
    float* __restrict__ sumOut, float* __restrict__ sqOut,
    int M, int N, int K) {
  (void)M;
  __shared__ __attribute__((aligned(16))) bf16 Asm[2][128 * 64];
  __shared__ __attribute__((aligned(16))) bf16 Bsm[2][256 * 64];
  const int tid = threadIdx.x;
  const int wv = tid >> 6, lane = tid & 63;
  const int quad = lane >> 4, l15 = lane & 15;
  const int wm = wv & 1, wn = wv >> 1;
  const int m0 = blockIdx.x * 128, n0 = blockIdx.y * 256;

  f32x4 acc[4][4];
#pragma unroll
  for (int i = 0; i < 4; ++i)
#pragma unroll
    for (int j = 0; j < 4; ++j) acc[i][j] = {0.f, 0.f, 0.f, 0.f};

  size_t aoff[2], boff[2];
  int slds[2];
#pragma unroll
  for (int i = 0; i < 2; ++i) {
    const int s = tid + i * 512;
    const int r = s >> 3, c = (s & 7) ^ (r & 7);
    aoff[i] = (size_t)(m0 + r) * K + c * 8;
    boff[i] = (size_t)(n0 + r) * K + c * 8;
    slds[i] = s * 8;
  }
  auto stageA = [&](int buf, int t) {
#pragma unroll
    for (int i = 0; i < 2; ++i) async16(A + aoff[i] + t * 64, &Asm[buf][slds[i]]);
  };
  auto stageB = [&](int buf, int hh, int t) {
    const size_t ho = (size_t)hh * 128 * K;
    const int hl = hh * 8192;
#pragma unroll
    for (int i = 0; i < 2; ++i)
      async16(Bt + boff[i] + ho + t * 64, &Bsm[buf][hl + slds[i]]);
  };

  stageB(0, 0, 0); stageB(0, 1, 0); stageA(0, 0);
  stageB(1, 0, 1); stageB(1, 1, 1); stageA(1, 1);
  VMWAIT(6);
  BAR();

  bf16x8 aF[2][2], bF0[2][2], bF1[2][2];
  const int am0 = wm * 64, bn0 = wn * 64;

  auto phases = [&](int ne, int no, bool hn) {
    ld_frags2(&Asm[0][0], am0, l15, quad, aF);
    ld_frags2(&Bsm[0][0], bn0, l15, quad, bF0);
    BAR();
    mma8<0, 0>(aF, bF0, acc);
    BAR();
    ld_frags2(&Bsm[0][0], bn0 + 32, l15, quad, bF1);
    BAR();
    mma8<0, 1>(aF, bF1, acc);
    BAR();
    ld_frags2(&Asm[0][0], am0 + 32, l15, quad, aF);
    if (hn) stageB(0, 0, ne);
    BAR();
    mma8<1, 1>(aF, bF1, acc);
    BAR();
    if (hn) stageB(0, 1, ne);
    BAR();
    mma8<1, 0>(aF, bF0, acc);
    if (hn) { VMWAIT(4); } else { VMWAIT(0); }
    BAR();
    ld_frags2(&Asm[1][0], am0, l15, quad, aF);
    ld_frags2(&Bsm[1][0], bn0, l15, quad, bF0);
    if (hn) stageA(0, ne);
    BAR();
    mma8<0, 0>(aF, bF0, acc);
    BAR();
    ld_frags2(&Bsm[1][0], bn0 + 32, l15, quad, bF1);
    BAR();
    mma8<0, 1>(aF, bF1, acc);
    BAR();
    ld_frags2(&Asm[1][0], am0 + 32, l15, quad, aF);
    if (hn) stageB(1, 0, no);
    BAR();
    mma8<1, 1>(aF, bF1, acc);
    BAR();
    if (hn) { stageB(1, 1, no); stageA(1, no); }
    BAR();
    mma8<1, 0>(aF, bF0, acc);
    if (hn) { VMWAIT(6); }
    BAR();
  };

  const int nIter = K >> 7;
  for (int it = 0; it + 1 < nIter; ++it) phases(2 * it + 2, 2 * it + 3, true);
  phases(0, 0, false);

  const int part = (MODE == 6) ? ((int)blockIdx.y >> 2) : 0;
  bf16* ob = o0;
  const float* bp = b0f;
  if constexpr (MODE == 6) {
    ob = (part == 0) ? o0 : (part == 1 ? o1 : o2);
    bp = (part == 0) ? b0f : (part == 1 ? b1f : b2f);
  }

  // hoist per-ni column constants
  float bvv[4], c1v[4], c2v[4];
  int cls[4];
#pragma unroll
  for (int ni = 0; ni < 4; ++ni) {
    const int col = n0 + wn * 64 + ni * 16 + l15;
    const int cl = (MODE == 6) ? (col - part * 1024) : col;
    cls[ni] = cl;
    bvv[ni] = bp[cl];
    if constexpr (MODE == 4) { c1v[ni] = b1f[col]; c2v[ni] = b2f[col]; }
    else { c1v[ni] = 0.f; c2v[ni] = 0.f; }
  }
  const float oscale = (MODE == 6 && part == 0) ? 0.045111758f : 1.0f;

#pragma unroll
  for (int mi = 0; mi < 4; ++mi) {
#pragma unroll
    for (int r = 0; r < 4; ++r) {
      const int row = m0 + wm * 64 + mi * 16 + quad * 4 + r;
      float rstd = 0.f, rmean = 0.f;
      if constexpr (MODE == 4) {
        const float s = sumIn[row], q = sqIn[row];
        const float mean = s * (1.0f / 1024.0f);
        const float var = q * (1.0f / 1024.0f) - mean * mean;
        rstd = rsqrtf(var + 1e-5f);
        rmean = -rstd * mean;
      }
      float ps = 0.f, pq = 0.f;
#pragma unroll
      for (int ni = 0; ni < 4; ++ni) {
        const int col = n0 + wn * 64 + ni * 16 + l15;
        const float a = acc[mi][ni][r];
        if constexpr (MODE == 1) {
          const size_t idx = (size_t)row * N + col;
          const float v = a + bvv[ni] + (float)residb[idx];
          o0[idx] = (bf16)v;
          ps += v; pq += v * v;
        } else if constexpr (MODE == 4) {
          const float v = rstd * a + rmean * c1v[ni] + c2v[ni] + bvv[ni];
          o0[(size_t)row * N + col] = (bf16)(v > 0.f ? v : 0.01f * v);
        } else if constexpr (MODE == 3) {
          const float v = 2.0f * (a + bvv[ni]);
          o0[(size_t)row * N + col] = (bf16)v;
          ps += v; pq += v * v;
        } else {  // MODE 6
          ob[(size_t)row * 1024 + cls[ni]] = (bf16)((a + bvv[ni]) * oscale);
        }
      }
      if constexpr (MODE == 1 || MODE == 3) {
        // reduce across the 16-lane quad group (xor<16 stays in-group)
        ps += __shfl_xor(ps, 1); pq += __shfl_xor(pq, 1);
        ps += __shfl_xor(ps, 2); pq += __shfl_xor(pq, 2);
        ps += __shfl_xor(ps, 4); pq += __shfl_xor(pq, 4);
        ps += __shfl_xor(ps, 8); pq += __shfl_xor(pq, 8);
        if (l15 == 0) {
          atomicAdd(&sumOut[row], ps);
          atomicAdd(&sqOut[row], pq);
        }
      }
    }
  }
}

// ---------------------------------------------------------------------------
// Fused mu|sig GEMM + reparameterization; LN-fold stats finalized inline from
// sum/sq accumulators (produced by W2 epilogue).
// Tile 32 rows x 256 cols, grid (256), 256 thr (4 waves).
__global__ __launch_bounds__(256) void gemm_musig_z(
    const bf16* __restrict__ A, const bf16* __restrict__ Bt,
    const float* __restrict__ sumP, const float* __restrict__ sqP,
    const float* __restrict__ c1, const float* __restrict__ c2,
    const float* __restrict__ bmu, const float* __restrict__ bsig,
    const float* __restrict__ eps, float* __restrict__ z) {
  __shared__ __attribute__((aligned(16))) bf16 Asm[2][32 * 64];
  __shared__ __attribute__((aligned(16))) bf16 Bsm[2][256 * 64];
  const int tid = threadIdx.x;
  const int wv = tid >> 6, lane = tid & 63;
  const int quad = lane >> 4, l15 = lane & 15;
  const int m0 = blockIdx.x * 32;

  f32x4 acc[2][4];
#pragma unroll
  for (int i = 0; i < 2; ++i)
#pragma unroll
    for (int j = 0; j < 4; ++j) acc[i][j] = {0.f, 0.f, 0.f, 0.f};

  const bf16* Ag;
  int as_;
  {
    const int s = tid;
    const int r = s >> 3, c = (s & 7) ^ (r & 7);
    Ag = A + (size_t)(m0 + r) * 1024 + c * 8;
    as_ = s * 8;
  }
  const bf16* Bg[8];
  int bs_[8];
#pragma unroll
  for (int i = 0; i < 8; ++i) {
    const int s = tid + i * 256;
    const int r = s >> 3, c = (s & 7) ^ (r & 7);
    Bg[i] = Bt + (size_t)r * 1024 + c * 8;
    bs_[i] = s * 8;
  }

  async16(Ag, &Asm[0][as_]);
#pragma unroll
  for (int i = 0; i < 8; ++i) async16(Bg[i], &Bsm[0][bs_[i]]);
  __syncthreads();

  for (int k = 0; k < 16; ++k) {
    const int cur = k & 1, nxt = cur ^ 1;
    bf16x8 af[2][2], bfr[4][2];
#pragma unroll
    for (int mi = 0; mi < 2; ++mi) {
      const int row = mi * 16 + l15;
#pragma unroll
      for (int h = 0; h < 2; ++h) {
        const int pos = (h * 4 + quad) ^ (row & 7);
        af[mi][h] = *(const bf16x8*)(&Asm[cur][(row * 8 + pos) * 8]);
      }
    }
#pragma unroll
    for (int ni = 0; ni < 4; ++ni) {
      const int nr = (ni < 2 ? wv * 32 + ni * 16 : 128 + wv * 32 + (ni - 2) * 16) + l15;
#pragma unroll
      for (int h = 0; h < 2; ++h) {
        const int pos = (h * 4 + quad) ^ (nr & 7);
        bfr[ni][h] = *(const bf16x8*)(&Bsm[cur][(nr * 8 + pos) * 8]);
      }
    }
    if (k + 1 < 16) {
      const int ko = (k + 1) * 64;
      async16(Ag + ko, &Asm[nxt][as_]);
#pragma unroll
      for (int i = 0; i < 8; ++i) async16(Bg[i] + ko, &Bsm[nxt][bs_[i]]);
    }
#pragma unroll
    for (int h = 0; h < 2; ++h)
#pragma unroll
      for (int mi = 0; mi < 2; ++mi)
#pragma unroll
        for (int ni = 0; ni < 4; ++ni)
          acc[mi][ni] = MFMA16(af[mi][h], bfr[ni][h], acc[mi][ni]);
    __syncthreads();
  }

#pragma unroll
  for (int mi = 0; mi < 2; ++mi) {
#pragma unroll
    for (int r = 0; r < 4; ++r) {
      const int row = m0 + mi * 16 + quad * 4 + r;
      const float s = sumP[row], q = sqP[row];
      const float mean = s * (1.0f / 1024.0f);
      const float var = q * (1.0f / 1024.0f) - mean * mean;
      const float rs = rsqrtf(var + 1e-5f);
      const float rm = -rs * mean;
#pragma unroll
      for (int cg = 0; cg < 2; ++cg) {
        const int cmu = wv * 32 + cg * 16 + l15;
        const int csg = 128 + cmu;
        const float mu = rs * acc[mi][cg][r] + rm * c1[cmu] + c2[cmu] + bmu[cmu];
        const float sg = rs * acc[mi][2 + cg][r] + rm * c1[csg] + c2[csg] + bsig[cmu];
        z[(size_t)row * 128 + cmu] = mu + __expf(sg) * eps[(size_t)row * 128 + cmu];
      }
    }
  }
}

// ---------------------------------------------------------------------------
// V transpose per head: Vb flat [256 bh][512 kv][64 d] -> VtG [256 bh][64 d][512 kv]
__global__ __launch_bounds__(256) void vtrans_kernel(const bf16* __restrict__ Vb,
                                                     bf16* __restrict__ VtG) {
  __shared__ float t[64][65];
  const int bh = blockIdx.x, kt = blockIdx.y;
  const int tid = threadIdx.x;
  const bf16* src = Vb + (size_t)bh * 32768 + (size_t)kt * 4096;
#pragma unroll
  for (int i = 0; i < 2; ++i) {
    int s = i * 256 + tid;
    int r = s >> 3, c = (s & 7) * 8;
    bf16x8 v = *(const bf16x8*)(src + (size_t)s * 8);
#pragma unroll
    for (int j = 0; j < 8; ++j) t[r][c + j] = (float)v[j];
  }
  __syncthreads();
  bf16* dst = VtG + (size_t)bh * 32768 + kt * 64;
#pragma unroll
  for (int i = 0; i < 2; ++i) {
    int s = i * 256 + tid;
    int d = s >> 3, kc = (s & 7) * 8;
    bf16 tmp[8];
#pragma unroll
    for (int j = 0; j < 8; ++j) tmp[j] = (bf16)t[kc + j][d];
    *(uint4*)(dst + (size_t)d * 512 + kc) = *(const uint4*)tmp;
  }
}

// ---------------------------------------------------------------------------
// Flash-style attention. grid (256 bh, 4 qblk), 256 threads (4 waves).
// No-max softmax: p = exp2(score_prescaled); Q already scaled by log2e/32
// in the QKV epilogue.
__global__ __launch_bounds__(256) void attn_kernel(const bf16* __restrict__ Qg,
                                                   const bf16* __restrict__ Kg,
                                                   const bf16* __restrict__ Vt,
                                                   bf16* __restrict__ ctx) {
  __shared__ __attribute__((aligned(16))) bf16 Ksm[128 * 64];
  __shared__ __attribute__((aligned(16))) bf16 Vsm[64 * 128];
  __shared__ __attribute__((aligned(16))) bf16 Psm[4][16 * 128];
  const int tid = threadIdx.x;
  const int w = tid >> 6, lane = tid & 63;
  const int quad = lane >> 4, l15 = lane & 15;
  const int bh = blockIdx.x;
  const size_t base = (size_t)bh * 32768;
  const bf16* Vth = Vt + base;
  const int qbase = blockIdx.y * 128 + w * 32;
  const f32x4 fz = {0.f, 0.f, 0.f, 0.f};

  bf16x8 a[2][2];
#pragma unroll
  for (int qt = 0; qt < 2; ++qt)
#pragma unroll
    for (int hf = 0; hf < 2; ++hf)
      a[qt][hf] = *(const bf16x8*)(Qg + base +
                   (size_t)(qbase + qt * 16 + l15) * 64 + hf * 32 + quad * 8);

  f32x4 o[2][4];
  float l_i[2][4];
#pragma unroll
  for (int qt = 0; qt < 2; ++qt)
#pragma unroll
    for (int i = 0; i < 4; ++i) { o[qt][i] = fz; l_i[qt][i] = 0.f; }

  for (int kv0 = 0; kv0 < 512; kv0 += 128) {
#pragma unroll
    for (int i = 0; i < 4; ++i) {
      int s = i * 256 + tid;
      int r = s >> 3, c = (s & 7) ^ (r & 7);
      async16(Kg + base + (size_t)(kv0 + r) * 64 + c * 8, &Ksm[s * 8]);
    }
#pragma unroll
    for (int i = 0; i < 4; ++i) {
      int s = i * 256 + tid;
      int d = s >> 4, cs = s & 15;
      int c = (cs & 8) | ((cs & 7) ^ (d & 7));
      async16(Vth + (size_t)d * 512 + kv0 + c * 8, &Vsm[s * 8]);
    }
    __syncthreads();

    f32x4 sc[2][8];
#pragma unroll
    for (int j = 0; j < 8; ++j) {
      const int n = j * 16 + l15;
      const bf16x8 k0 = *(const bf16x8*)(&Ksm[(n * 8 + (quad ^ (n & 7))) * 8]);
      const bf16x8 k1 = *(const bf16x8*)(&Ksm[(n * 8 + ((4 + quad) ^ (n & 7))) * 8]);
      sc[0][j] = MFMA16(a[0][0], k0, fz);
      sc[0][j] = MFMA16(a[0][1], k1, sc[0][j]);
      sc[1][j] = MFMA16(a[1][0], k0, fz);
      sc[1][j] = MFMA16(a[1][1], k1, sc[1][j]);
    }

    bf16* ps = &Psm[w][0];
#pragma unroll
    for (int qt = 0; qt < 2; ++qt) {
#pragma unroll
      for (int r = 0; r < 4; ++r) {
        const int prow = quad * 4 + r;
        float sum = 0.f;
#pragma unroll
        for (int j = 0; j < 8; ++j) {
          const float p = EXP2F(sc[qt][j][r]);
          sum += p;
          const int col = j * 16 + l15;
          const int cc = col >> 3;
          const int ccs = (cc & 8) | ((cc & 7) ^ (prow & 7));
          ps[prow * 128 + ccs * 8 + (col & 7)] = (bf16)p;
        }
        l_i[qt][r] += sum;
      }
#pragma unroll
      for (int c32 = 0; c32 < 4; ++c32) {
        const int pc = c32 * 4 + quad;
        const int pcs = (pc & 8) | ((pc & 7) ^ (l15 & 7));
        const bf16x8 pf = *(const bf16x8*)(ps + l15 * 128 + pcs * 8);
#pragma unroll
        for (int ni = 0; ni < 4; ++ni) {
          const int d = ni * 16 + l15;
          const int vcs = (pc & 8) | ((pc & 7) ^ (d & 7));
          const bf16x8 vf = *(const bf16x8*)(&Vsm[(d * 16 + vcs) * 8]);
          o[qt][ni] = MFMA16(pf, vf, o[qt][ni]);
        }
      }
    }
    __syncthreads();
  }

#pragma unroll
  for (int qt = 0; qt < 2; ++qt) {
#pragma unroll
    for (int r = 0; r < 4; ++r) {
      float l = l_i[qt][r];
      l += __shfl_xor(l, 1);
      l += __shfl_xor(l, 2);
      l += __shfl_xor(l, 4);
      l += __shfl_xor(l, 8);
      const float inv = 1.0f / l;
#pragma unroll
      for (int ni = 0; ni < 4; ++ni)
        ctx[base + (size_t)(qbase + qt * 16 + quad * 4 + r) * 64 + ni * 16 + l15]
            = (bf16)(o[qt][ni][r] * inv);
    }
  }
}

// ---------------------------------------------------------------------------
extern "C" void kernel_launch(void* const* d_in, const int* in_sizes, int n_in,
                              void* d_out, int out_size, void* d_ws, size_t ws_size,
                              hipStream_t stream) {
  (void)in_sizes; (void)n_in; (void)out_size; (void)ws_size;
  const int* x = (const int*)d_in[0];
  const float* emb = (const float*)d_in[1];
  const float* Wq = (const float*)d_in[2];
  const float* bq = (const float*)d_in[3];
  const float* Wk = (const float*)d_in[4];
  const float* bkb = (const float*)d_in[5];
  const float* Wv = (const float*)d_in[6];
  const float* bv = (const float*)d_in[7];
  const float* Wo = (const float*)d_in[8];
  const float* bo = (const float*)d_in[9];
  const float* g1 = (const float*)d_in[10];
  const float* be1 = (const float*)d_in[11];
  const float* W1 = (const float*)d_in[12];
  const float* bf1 = (const float*)d_in[13];
  const float* W2 = (const float*)d_in[14];
  const float* bf2 = (const float*)d_in[15];
  const float* g2 = (const float*)d_in[16];
  const float* be2 = (const float*)d_in[17];
  const float* g3 = (const float*)d_in[18];
  const float* be3 = (const float*)d_in[19];
  const float* Wmu = (const float*)d_in[20];
  const float* bmu = (const float*)d_in[21];
  const float* Wsig = (const float*)d_in[22];
  const float* bsig = (const float*)d_in[23];
  const float* eps = (const float*)d_in[24];
  float* z = (float*)d_out;

  const int M = 8192, D = 1024;
  char* ws = (char*)d_ws;
  size_t off = 0;
  auto alloc = [&](size_t b) {
    char* p = ws + off;
    off += (b + 255) & ~(size_t)255;
    return p;
  };
  bf16* wqkvT = (bf16*)alloc((size_t)3072 * 1024 * 2);  // [wq^T; wk^T; wv^T]
  bf16* woT = (bf16*)alloc((size_t)1024 * 1024 * 2);
  bf16* w1T = (bf16*)alloc((size_t)1024 * 1024 * 2);    // g2-scaled
  bf16* w2T = (bf16*)alloc((size_t)1024 * 1024 * 2);
  bf16* wmsT = (bf16*)alloc((size_t)256 * 1024 * 2);    // g3-scaled [Wmu^T;Wsig^T]
  bf16* hb = (bf16*)alloc((size_t)M * D * 2);           // h1 (resid for Wo)
  bf16* Qb = (bf16*)alloc((size_t)M * D * 2);
  bf16* Kb = (bf16*)alloc((size_t)M * D * 2);
  bf16* Vb = (bf16*)alloc((size_t)M * D * 2);
  bf16* VtG = (bf16*)alloc((size_t)M * D * 2);
  bf16* Cb = (bf16*)alloc((size_t)M * D * 2);           // ctx
  bf16* h2b = (bf16*)alloc((size_t)M * D * 2);
  bf16* hidb = (bf16*)alloc((size_t)M * D * 2);
  bf16* h4b = (bf16*)alloc((size_t)M * D * 2);
  // contiguous accumulator block (zeroed by embed kernel): coefs + row sums
  float* coefs = (float*)alloc((size_t)35328 * 4);
  float* c1w1 = coefs;            // 1024
  float* c2w1 = coefs + 1024;     // 1024
  float* c1ms = coefs + 2048;     // 256
  float* c2ms = coefs + 2304;     // 256
  float* sum2 = coefs + 2560;     // 8192
  float* sq2 = coefs + 10752;     // 8192
  float* sum3 = coefs + 18944;    // 8192
  float* sq3 = coefs + 27136;     // 8192 (end 35328)

  dim3 b256(256);
  dim3 b512(512);

  // embed+LN1 (2048 blocks) + accumulator zeroing (138 blocks), runs first
  embed_ln_kernel<<<2186, b256, 0, stream>>>(x, emb, g1, be1, hb, coefs);

  TP8 tp;
  for (int i = 0; i < 8; ++i) {
    tp.gsrc[i] = nullptr; tp.besrc[i] = nullptr;
    tp.c1dst[i] = nullptr; tp.c2dst[i] = nullptr;
  }
  tp.src[0] = Wq;   tp.dst[0] = wqkvT;                        tp.ncol[0] = 1024;
  tp.src[1] = Wk;   tp.dst[1] = wqkvT + (size_t)1024 * 1024;  tp.ncol[1] = 1024;
  tp.src[2] = Wv;   tp.dst[2] = wqkvT + (size_t)2048 * 1024;  tp.ncol[2] = 1024;
  tp.src[3] = Wo;   tp.dst[3] = woT;                          tp.ncol[3] = 1024;
  tp.src[4] = W1;   tp.dst[4] = w1T;   tp.ncol[4] = 1024;
  tp.gsrc[4] = g2;  tp.besrc[4] = be2; tp.c1dst[4] = c1w1;    tp.c2dst[4] = c2w1;
  tp.src[5] = W2;   tp.dst[5] = w2T;                          tp.ncol[5] = 1024;
  tp.src[6] = Wmu;  tp.dst[6] = wmsT;  tp.ncol[6] = 128;
  tp.gsrc[6] = g3;  tp.besrc[6] = be3; tp.c1dst[6] = c1ms;    tp.c2dst[6] = c2ms;
  tp.src[7] = Wsig; tp.dst[7] = wmsT + (size_t)128 * 1024;    tp.ncol[7] = 128;
  tp.gsrc[7] = g3;  tp.besrc[7] = be3; tp.c1dst[7] = c1ms + 128; tp.c2dst[7] = c2ms + 128;
  transpose8_kernel<<<dim3(16, 16, 8), b256, 0, stream>>>(tp);

  // fused QKV: N=3072, outputs routed to Qb/Kb/Vb (Q prescaled by log2e/32).
  gemm8_kernel<6><<<dim3(64, 12), b512, 0, stream>>>(hb, wqkvT, bq, bkb, bv,
                                                     Qb, Kb, Vb, nullptr,
                                                     nullptr, nullptr, nullptr,
                                                     nullptr, M, 3072, D);
  vtrans_kernel<<<dim3(256, 8), b256, 0, stream>>>(Vb, VtG);
  attn_kernel<<<dim3(256, 4), b256, 0, stream>>>(Qb, Kb, VtG, Cb);

  // Wo + resid -> h2b; accumulates LN2 row sums
  gemm8_kernel<1><<<dim3(64, 4), b512, 0, stream>>>(Cb, woT, bo, nullptr, nullptr,
                                                    h2b, nullptr, nullptr, hb,
                                                    nullptr, nullptr, sum2, sq2,
                                                    M, D, D);
  // W1 with LN2-fold finalized inline from sums
  gemm8_kernel<4><<<dim3(64, 4), b512, 0, stream>>>(h2b, w1T, bf1, c1w1, c2w1,
                                                    hidb, nullptr, nullptr, nullptr,
                                                    sum2, sq2, nullptr, nullptr,
                                                    M, D, D);
  // W2 (f+f) -> h4b; accumulates LN3 row sums
  gemm8_kernel<3><<<dim3(64, 4), b512, 0, stream>>>(hidb, w2T, bf2, nullptr, nullptr,
                                                    h4b, nullptr, nullptr, nullptr,
                                                    nullptr, nullptr, sum3, sq3,
                                                    M, D, D);
  // fused mu/sig/z with LN3-fold finalized inline
  gemm_musig_z<<<dim3(256), b256, 0, stream>>>(h4b, wmsT, sum3, sq3, c1ms, c2ms,
                                               bmu, bsig, eps, z);
}